// Round 1
// baseline (1604.301 us; speedup 1.0000x reference)
//
#include <hip/hip_runtime.h>
#include <hip/hip_fp16.h>

#define B_ 16
#define N_ 785
#define C_ 768
#define H_ 12
#define HD_ 64
#define P_ 48
#define M_ (B_*N_)      // 12560
#define TC_ (3*C_)      // 2304
#define POSW 800        // padded row stride for pos bias (16B-aligned fp16 rows)
#define SCALE 0.125f    // hd^-0.5

// ws layout (fp16 elements)
#define OFF_Q   0
#define OFF_K   9646080
#define OFF_V   19292160
#define OFF_POS 28938240                  // size 12*785*800 = 7,536,000
#define OFF_AO  36474240                  // attn output [B,N,C] fp16

struct __align__(16) Half8 { __half h[8]; };

// ---------------------------------------------------------------------------
// K1: qkv = x @ qkv_w^T, scatter to q (pre-scaled), k, v in [B,H,N,64] fp16
// ---------------------------------------------------------------------------
__global__ __launch_bounds__(256) void qkv_gemm(
    const float* __restrict__ x, const float* __restrict__ w,
    __half* __restrict__ qh, __half* __restrict__ kh, __half* __restrict__ vh)
{
    __shared__ float As[16][136];
    __shared__ float Bs[16][136];
    const int t  = threadIdx.x;
    const int m0 = blockIdx.x * 128;
    const int n0 = blockIdx.y * 128;
    const int tr = t >> 4, tc = t & 15;
    const int i0 = tr * 8, j0 = tc * 8;

    float acc[8][8];
    #pragma unroll
    for (int i = 0; i < 8; ++i)
        #pragma unroll
        for (int j = 0; j < 8; ++j) acc[i][j] = 0.f;

    for (int k0 = 0; k0 < 768; k0 += 16) {
        #pragma unroll
        for (int l = 0; l < 2; ++l) {
            int f = t + l * 256;
            int row = f >> 2, c4 = (f & 3) * 4;
            int gm = m0 + row;
            float4 va = make_float4(0.f, 0.f, 0.f, 0.f);
            if (gm < M_) va = *(const float4*)&x[gm * 768 + k0 + c4];
            As[c4+0][row] = va.x; As[c4+1][row] = va.y;
            As[c4+2][row] = va.z; As[c4+3][row] = va.w;
            float4 vb = *(const float4*)&w[(n0 + row) * 768 + k0 + c4];
            Bs[c4+0][row] = vb.x; Bs[c4+1][row] = vb.y;
            Bs[c4+2][row] = vb.z; Bs[c4+3][row] = vb.w;
        }
        __syncthreads();
        #pragma unroll
        for (int k = 0; k < 16; ++k) {
            float a[8], b[8];
            *(float4*)&a[0] = *(const float4*)&As[k][i0];
            *(float4*)&a[4] = *(const float4*)&As[k][i0 + 4];
            *(float4*)&b[0] = *(const float4*)&Bs[k][j0];
            *(float4*)&b[4] = *(const float4*)&Bs[k][j0 + 4];
            #pragma unroll
            for (int i = 0; i < 8; ++i)
                #pragma unroll
                for (int j = 0; j < 8; ++j)
                    acc[i][j] = fmaf(a[i], b[j], acc[i][j]);
        }
        __syncthreads();
    }

    #pragma unroll
    for (int i = 0; i < 8; ++i) {
        int m = m0 + i0 + i;
        if (m >= M_) continue;
        int bb = m / N_, nn = m - bb * N_;
        #pragma unroll
        for (int j = 0; j < 8; ++j) {
            int o = n0 + j0 + j;
            int tsel = o / 768;
            int rr = o - tsel * 768;
            int hh = rr >> 6, dd = rr & 63;
            int dst = ((bb * H_ + hh) * N_ + nn) * HD_ + dd;
            float v = acc[i][j];
            if (tsel == 0)      qh[dst] = __float2half(v * SCALE);
            else if (tsel == 1) kh[dst] = __float2half(v);
            else                vh[dst] = __float2half(v);
        }
    }
}

// ---------------------------------------------------------------------------
// K2: pos bias: posh[h][n][m] = SCALE * sum_p pos_emb[n][m][p] * pw[h][p]
// ---------------------------------------------------------------------------
__global__ __launch_bounds__(256) void pos_kernel(
    const float* __restrict__ pe, const float* __restrict__ pw,
    __half* __restrict__ posh)
{
    __shared__ float W[H_][P_];
    const int t = threadIdx.x;
    for (int i = t; i < H_ * P_; i += 256) W[i / P_][i % P_] = pw[i];
    __syncthreads();
    int nm = blockIdx.x * 256 + t;
    if (nm >= N_ * N_) return;
    float e[48];
    const float4* src = (const float4*)(pe + (size_t)nm * 48);
    #pragma unroll
    for (int i = 0; i < 12; ++i) {
        float4 v = src[i];
        e[4*i] = v.x; e[4*i+1] = v.y; e[4*i+2] = v.z; e[4*i+3] = v.w;
    }
    int n = nm / N_, m = nm - n * N_;
    #pragma unroll
    for (int hh = 0; hh < H_; ++hh) {
        float s = 0.f;
        #pragma unroll
        for (int p = 0; p < 48; ++p) s = fmaf(e[p], W[hh][p], s);
        posh[(hh * N_ + n) * POSW + m] = __float2half(s * SCALE);
    }
}

// ---------------------------------------------------------------------------
// K3: flash attention per (b,h): 32-query tile, 64-key chunks, fp32 compute
// ---------------------------------------------------------------------------
__global__ __launch_bounds__(256) void attn_kernel(
    const __half* __restrict__ qh, const __half* __restrict__ kh,
    const __half* __restrict__ vh, const __half* __restrict__ posh,
    __half* __restrict__ aoh)
{
    __shared__ float Qs[32][72];
    __shared__ float Ks[64][72];
    __shared__ float Vs[64][72];
    __shared__ float Ss[32][72];
    __shared__ float mrow[32], lrow[32], arow[32];

    const int t  = threadIdx.x;
    const int bh = blockIdx.x;           // b*12 + h
    const int h  = bh % H_;
    const int n0 = blockIdx.y * 32;
    const int nq = min(32, N_ - n0);

    // load Q tile (pre-scaled by SCALE in K1)
    {
        int row = t >> 3, cg = (t & 7) * 8;
        float4 f0 = make_float4(0.f,0.f,0.f,0.f);
        float4 f1 = make_float4(0.f,0.f,0.f,0.f);
        if (row < nq) {
            Half8 q8 = *(const Half8*)&qh[(bh * N_ + n0 + row) * HD_ + cg];
            f0.x = __half2float(q8.h[0]); f0.y = __half2float(q8.h[1]);
            f0.z = __half2float(q8.h[2]); f0.w = __half2float(q8.h[3]);
            f1.x = __half2float(q8.h[4]); f1.y = __half2float(q8.h[5]);
            f1.z = __half2float(q8.h[6]); f1.w = __half2float(q8.h[7]);
        }
        *(float4*)&Qs[row][cg]     = f0;
        *(float4*)&Qs[row][cg + 4] = f1;
    }
    if (t < 32) { mrow[t] = -1e30f; lrow[t] = 0.f; }

    float O[8] = {0.f,0.f,0.f,0.f,0.f,0.f,0.f,0.f};
    const int r  = t >> 3;               // PV/softmax row (0..31)
    const int dg = (t & 7) * 8;          // PV d-block
    const int tq = t & 15, tj = t >> 4;  // QK mapping
    __syncthreads();

    for (int c = 0; c < 13; ++c) {
        const int m0 = c * 64;
        const int mc = min(64, N_ - m0);
        // stage K/V chunk
        {
            int row = t >> 2, cg = (t & 3) * 16;
            if (row < mc) {
                int base = (bh * N_ + m0 + row) * HD_ + cg;
                Half8 ka = *(const Half8*)&kh[base];
                Half8 kb = *(const Half8*)&kh[base + 8];
                Half8 va = *(const Half8*)&vh[base];
                Half8 vb = *(const Half8*)&vh[base + 8];
                #pragma unroll
                for (int e = 0; e < 8; ++e) {
                    Ks[row][cg + e]     = __half2float(ka.h[e]);
                    Ks[row][cg + 8 + e] = __half2float(kb.h[e]);
                    Vs[row][cg + e]     = __half2float(va.h[e]);
                    Vs[row][cg + 8 + e] = __half2float(vb.h[e]);
                }
            } else {
                #pragma unroll
                for (int e = 0; e < 16; ++e) { Ks[row][cg + e] = 0.f; Vs[row][cg + e] = 0.f; }
            }
        }
        // stage pos bias into Ss
        {
            int pr = t >> 3, pc = (t & 7) * 8;
            float4 z0 = make_float4(0.f,0.f,0.f,0.f);
            float4 z1 = make_float4(0.f,0.f,0.f,0.f);
            if (n0 + pr < N_) {
                Half8 p8 = *(const Half8*)&posh[(h * N_ + n0 + pr) * POSW + m0 + pc];
                z0.x = __half2float(p8.h[0]); z0.y = __half2float(p8.h[1]);
                z0.z = __half2float(p8.h[2]); z0.w = __half2float(p8.h[3]);
                z1.x = __half2float(p8.h[4]); z1.y = __half2float(p8.h[5]);
                z1.z = __half2float(p8.h[6]); z1.w = __half2float(p8.h[7]);
            }
            *(float4*)&Ss[pr][pc]     = z0;
            *(float4*)&Ss[pr][pc + 4] = z1;
        }
        __syncthreads();
        // QK^T: 2 queries x 4 keys per thread, bias pre-loaded in Ss
        {
            float s0[4], s1[4];
            #pragma unroll
            for (int b2 = 0; b2 < 4; ++b2) {
                s0[b2] = Ss[tq][4 * tj + b2];
                s1[b2] = Ss[tq + 16][4 * tj + b2];
            }
            #pragma unroll 8
            for (int d = 0; d < 64; ++d) {
                float q0 = Qs[tq][d], q1 = Qs[tq + 16][d];
                float k0v = Ks[4*tj+0][d], k1v = Ks[4*tj+1][d];
                float k2v = Ks[4*tj+2][d], k3v = Ks[4*tj+3][d];
                s0[0] = fmaf(q0, k0v, s0[0]); s0[1] = fmaf(q0, k1v, s0[1]);
                s0[2] = fmaf(q0, k2v, s0[2]); s0[3] = fmaf(q0, k3v, s0[3]);
                s1[0] = fmaf(q1, k0v, s1[0]); s1[1] = fmaf(q1, k1v, s1[1]);
                s1[2] = fmaf(q1, k2v, s1[2]); s1[3] = fmaf(q1, k3v, s1[3]);
            }
            #pragma unroll
            for (int b2 = 0; b2 < 4; ++b2) {
                int j = 4 * tj + b2;
                bool valid = (m0 + j) < N_;
                Ss[tq][j]      = valid ? s0[b2] : -1e30f;
                Ss[tq + 16][j] = valid ? s1[b2] : -1e30f;
            }
        }
        __syncthreads();
        // online softmax over the 64-key chunk
        {
            const int g = t & 7;
            float pm = -1e30f;
            #pragma unroll
            for (int k = 0; k < 8; ++k) pm = fmaxf(pm, Ss[r][g * 8 + k]);
            pm = fmaxf(pm, __shfl_xor(pm, 1));
            pm = fmaxf(pm, __shfl_xor(pm, 2));
            pm = fmaxf(pm, __shfl_xor(pm, 4));
            float mold = mrow[r];
            float mnew = fmaxf(mold, pm);
            float al   = __expf(mold - mnew);
            float ps = 0.f;
            #pragma unroll
            for (int k = 0; k < 8; ++k) {
                float p = __expf(Ss[r][g * 8 + k] - mnew);
                Ss[r][g * 8 + k] = p;
                ps += p;
            }
            ps += __shfl_xor(ps, 1);
            ps += __shfl_xor(ps, 2);
            ps += __shfl_xor(ps, 4);
            if (g == 0) { arow[r] = al; mrow[r] = mnew; lrow[r] = lrow[r] * al + ps; }
        }
        __syncthreads();
        // rescale + PV
        {
            float al = arow[r];
            #pragma unroll
            for (int k = 0; k < 8; ++k) O[k] *= al;
            #pragma unroll 4
            for (int j = 0; j < 64; ++j) {
                float p = Ss[r][j];
                float4 v0 = *(const float4*)&Vs[j][dg];
                float4 v1 = *(const float4*)&Vs[j][dg + 4];
                O[0] = fmaf(p, v0.x, O[0]); O[1] = fmaf(p, v0.y, O[1]);
                O[2] = fmaf(p, v0.z, O[2]); O[3] = fmaf(p, v0.w, O[3]);
                O[4] = fmaf(p, v1.x, O[4]); O[5] = fmaf(p, v1.y, O[5]);
                O[6] = fmaf(p, v1.z, O[6]); O[7] = fmaf(p, v1.w, O[7]);
            }
        }
        __syncthreads();
    }

    if (r < nq) {
        float inv = 1.f / lrow[r];
        int bb = bh / H_;
        Half8 o8;
        #pragma unroll
        for (int k = 0; k < 8; ++k) o8.h[k] = __float2half(O[k] * inv);
        *(Half8*)&aoh[((size_t)(bb * N_ + n0 + r)) * C_ + h * HD_ + dg] = o8;
    }
}

// ---------------------------------------------------------------------------
// K4: out = aoh @ proj_w^T + proj_b   (fp32 out)
// ---------------------------------------------------------------------------
__global__ __launch_bounds__(256) void proj_gemm(
    const __half* __restrict__ a, const float* __restrict__ w,
    const float* __restrict__ bias, float* __restrict__ out)
{
    __shared__ float As[16][136];
    __shared__ float Bs[16][136];
    const int t  = threadIdx.x;
    const int m0 = blockIdx.x * 128;
    const int n0 = blockIdx.y * 128;
    const int tr = t >> 4, tc = t & 15;
    const int i0 = tr * 8, j0 = tc * 8;

    float acc[8][8];
    #pragma unroll
    for (int i = 0; i < 8; ++i)
        #pragma unroll
        for (int j = 0; j < 8; ++j) acc[i][j] = 0.f;

    for (int k0 = 0; k0 < 768; k0 += 16) {
        {
            int row = t >> 1, cg = (t & 1) * 8;
            int gm = m0 + row;
            if (gm < M_) {
                Half8 a8 = *(const Half8*)&a[(size_t)gm * 768 + k0 + cg];
                #pragma unroll
                for (int e = 0; e < 8; ++e) As[cg + e][row] = __half2float(a8.h[e]);
            } else {
                #pragma unroll
                for (int e = 0; e < 8; ++e) As[cg + e][row] = 0.f;
            }
        }
        #pragma unroll
        for (int l = 0; l < 2; ++l) {
            int f = t + l * 256;
            int row = f >> 2, c4 = (f & 3) * 4;
            float4 u = *(const float4*)&w[(n0 + row) * 768 + k0 + c4];
            Bs[c4+0][row] = u.x; Bs[c4+1][row] = u.y;
            Bs[c4+2][row] = u.z; Bs[c4+3][row] = u.w;
        }
        __syncthreads();
        #pragma unroll
        for (int k = 0; k < 16; ++k) {
            float av[8], bv[8];
            *(float4*)&av[0] = *(const float4*)&As[k][i0];
            *(float4*)&av[4] = *(const float4*)&As[k][i0 + 4];
            *(float4*)&bv[0] = *(const float4*)&Bs[k][j0];
            *(float4*)&bv[4] = *(const float4*)&Bs[k][j0 + 4];
            #pragma unroll
            for (int i = 0; i < 8; ++i)
                #pragma unroll
                for (int j = 0; j < 8; ++j)
                    acc[i][j] = fmaf(av[i], bv[j], acc[i][j]);
        }
        __syncthreads();
    }

    #pragma unroll
    for (int i = 0; i < 8; ++i) {
        int m = m0 + i0 + i;
        if (m >= M_) continue;
        #pragma unroll
        for (int j = 0; j < 8; ++j) {
            int o = n0 + j0 + j;
            out[(size_t)m * 768 + o] = acc[i][j] + bias[o];
        }
    }
}

// ---------------------------------------------------------------------------
extern "C" void kernel_launch(void* const* d_in, const int* in_sizes, int n_in,
                              void* d_out, int out_size, void* d_ws, size_t ws_size,
                              hipStream_t stream)
{
    const float* x     = (const float*)d_in[0];
    const float* qkv_w = (const float*)d_in[1];
    const float* pe    = (const float*)d_in[2];
    const float* pw    = (const float*)d_in[3];
    const float* pjw   = (const float*)d_in[4];
    const float* pjb   = (const float*)d_in[5];
    float* out = (float*)d_out;

    __half* wsh  = (__half*)d_ws;
    __half* qh   = wsh + OFF_Q;
    __half* kh   = wsh + OFF_K;
    __half* vh   = wsh + OFF_V;
    __half* posh = wsh + OFF_POS;
    __half* aoh  = wsh + OFF_AO;

    qkv_gemm<<<dim3(99, 18), 256, 0, stream>>>(x, qkv_w, qh, kh, vh);
    pos_kernel<<<dim3((N_ * N_ + 255) / 256), 256, 0, stream>>>(pe, pw, posh);
    attn_kernel<<<dim3(192, 25), 256, 0, stream>>>(qh, kh, vh, posh, aoh);
    proj_gemm<<<dim3(99, 6), 256, 0, stream>>>(aoh, pjw, pjb, out);
}

// Round 2
// 963.732 us; speedup vs baseline: 1.6647x; 1.6647x over previous
//
#include <hip/hip_runtime.h>
#include <hip/hip_fp16.h>

#define B_ 16
#define N_ 785
#define C_ 768
#define H_ 12
#define HD_ 64
#define P_ 48
#define M_ (B_*N_)      // 12560
#define POSW 800        // padded row stride (halves) for pos bias
#define VTW  800        // padded row stride (halves) for V^T
#define SCALE 0.125f    // hd^-0.5

// ws layout (fp16 element offsets)
#define OFF_Q   0                         //  9,646,080
#define OFF_K   9646080                   //  9,646,080
#define OFF_VT  19292160                  // 16*12*64*800 = 9,830,400
#define OFF_POS 29122560                  // 12*785*800   = 7,536,000
#define OFF_AO  36658560                  //  9,646,080  (end 46,304,640 halves)

struct __align__(16) Half8 { __half h[8]; };
typedef _Float16 half8_t __attribute__((ext_vector_type(8)));
typedef float f32x4 __attribute__((ext_vector_type(4)));

// ---------------------------------------------------------------------------
// K1: qkv = x @ qkv_w^T; scatter q (pre-scaled) / k row-major, v TRANSPOSED
// ---------------------------------------------------------------------------
__global__ __launch_bounds__(256) void qkv_gemm(
    const float* __restrict__ x, const float* __restrict__ w,
    __half* __restrict__ qh, __half* __restrict__ kh, __half* __restrict__ vth)
{
    __shared__ float As[16][136];
    __shared__ float Bs[16][136];
    const int t  = threadIdx.x;
    const int m0 = blockIdx.x * 128;
    const int n0 = blockIdx.y * 128;
    const int tr = t >> 4, tc = t & 15;
    const int i0 = tr * 8, j0 = tc * 8;

    float acc[8][8];
    #pragma unroll
    for (int i = 0; i < 8; ++i)
        #pragma unroll
        for (int j = 0; j < 8; ++j) acc[i][j] = 0.f;

    for (int k0 = 0; k0 < 768; k0 += 16) {
        #pragma unroll
        for (int l = 0; l < 2; ++l) {
            int f = t + l * 256;
            int row = f >> 2, c4 = (f & 3) * 4;
            int gm = m0 + row;
            float4 va = make_float4(0.f, 0.f, 0.f, 0.f);
            if (gm < M_) va = *(const float4*)&x[gm * 768 + k0 + c4];
            As[c4+0][row] = va.x; As[c4+1][row] = va.y;
            As[c4+2][row] = va.z; As[c4+3][row] = va.w;
            float4 vb = *(const float4*)&w[(n0 + row) * 768 + k0 + c4];
            Bs[c4+0][row] = vb.x; Bs[c4+1][row] = vb.y;
            Bs[c4+2][row] = vb.z; Bs[c4+3][row] = vb.w;
        }
        __syncthreads();
        #pragma unroll
        for (int k = 0; k < 16; ++k) {
            float a[8], b[8];
            *(float4*)&a[0] = *(const float4*)&As[k][i0];
            *(float4*)&a[4] = *(const float4*)&As[k][i0 + 4];
            *(float4*)&b[0] = *(const float4*)&Bs[k][j0];
            *(float4*)&b[4] = *(const float4*)&Bs[k][j0 + 4];
            #pragma unroll
            for (int i = 0; i < 8; ++i)
                #pragma unroll
                for (int j = 0; j < 8; ++j)
                    acc[i][j] = fmaf(a[i], b[j], acc[i][j]);
        }
        __syncthreads();
    }

    #pragma unroll
    for (int i = 0; i < 8; ++i) {
        int m = m0 + i0 + i;
        if (m >= M_) continue;
        int bb = m / N_, nn = m - bb * N_;
        #pragma unroll
        for (int j = 0; j < 8; ++j) {
            int o = n0 + j0 + j;
            int tsel = o / 768;
            int rr = o - tsel * 768;
            int hh = rr >> 6, dd = rr & 63;
            float v = acc[i][j];
            if (tsel == 0)
                qh[((bb * H_ + hh) * N_ + nn) * HD_ + dd] = __float2half(v * SCALE);
            else if (tsel == 1)
                kh[((bb * H_ + hh) * N_ + nn) * HD_ + dd] = __float2half(v);
            else
                vth[(size_t)((bb * H_ + hh) * HD_ + dd) * VTW + nn] = __float2half(v);
        }
    }
}

// ---------------------------------------------------------------------------
// K2: pos bias: posh[h][n][m] = SCALE * sum_p pos_emb[n][m][p] * pw[h][p]
// ---------------------------------------------------------------------------
__global__ __launch_bounds__(256) void pos_kernel(
    const float* __restrict__ pe, const float* __restrict__ pw,
    __half* __restrict__ posh)
{
    __shared__ float W[H_][P_];
    const int t = threadIdx.x;
    for (int i = t; i < H_ * P_; i += 256) W[i / P_][i % P_] = pw[i];
    __syncthreads();
    int nm = blockIdx.x * 256 + t;
    if (nm >= N_ * N_) return;
    float e[48];
    const float4* src = (const float4*)(pe + (size_t)nm * 48);
    #pragma unroll
    for (int i = 0; i < 12; ++i) {
        float4 v = src[i];
        e[4*i] = v.x; e[4*i+1] = v.y; e[4*i+2] = v.z; e[4*i+3] = v.w;
    }
    int n = nm / N_, m = nm - n * N_;
    #pragma unroll
    for (int hh = 0; hh < H_; ++hh) {
        float s = 0.f;
        #pragma unroll
        for (int p = 0; p < 48; ++p) s = fmaf(e[p], W[hh][p], s);
        posh[((size_t)hh * N_ + n) * POSW + m] = __float2half(s * SCALE);
    }
}

// ---------------------------------------------------------------------------
// K3: MFMA flash attention. Block = (qtile of 64, bh). 4 waves x 16 q-rows.
// ---------------------------------------------------------------------------
__global__ __launch_bounds__(256) void attn_mfma(
    const _Float16* __restrict__ qh, const _Float16* __restrict__ kh,
    const _Float16* __restrict__ vt, const _Float16* __restrict__ posh,
    _Float16* __restrict__ aoh)
{
    __shared__ _Float16 Kl[64][72];          // keys  [m][d]
    __shared__ _Float16 Vl[64][72];          // V^T   [d][m]
    __shared__ _Float16 Bl[64][72];          // bias  [qrow][m]
    __shared__ _Float16 Pl[4][16][72];       // per-wave P [qrow][m]

    const int t  = threadIdx.x;
    const int w  = t >> 6;                   // wave 0..3
    const int l  = t & 63;
    const int lr = l & 15;                   // fragment row/col
    const int lg = l >> 4;                   // k-group 0..3
    const int bh = blockIdx.y;
    const int h  = bh % H_;
    const int n0 = blockIdx.x * 64;

    // Q fragments for this wave's 16 rows (held all loop; pre-scaled in K1)
    const int qrow = n0 + w * 16 + lr;
    const int qrc  = qrow < N_ ? qrow : N_ - 1;
    const half8_t qf0 = *(const half8_t*)(qh + ((size_t)bh * N_ + qrc) * HD_ + lg * 8);
    const half8_t qf1 = *(const half8_t*)(qh + ((size_t)bh * N_ + qrc) * HD_ + 32 + lg * 8);

    f32x4 O0 = {0.f,0.f,0.f,0.f}, O1 = O0, O2 = O0, O3 = O0;
    float mr[4] = {-1e30f, -1e30f, -1e30f, -1e30f};
    float ls[4] = {0.f, 0.f, 0.f, 0.f};

    const int srow = t >> 2;                 // staging row 0..63
    const int scol = (t & 3) * 16;           // staging col 0/16/32/48

    for (int c = 0; c < 13; ++c) {
        const int m0 = c * 64;
        // ---- cooperative staging: K, V^T, bias (clamped rows; cols masked later)
        {
            const int gm = (m0 + srow) < N_ ? (m0 + srow) : N_ - 1;
            const half8_t* ksrc = (const half8_t*)(kh + ((size_t)bh * N_ + gm) * HD_ + scol);
            *(half8_t*)&Kl[srow][scol]     = ksrc[0];
            *(half8_t*)&Kl[srow][scol + 8] = ksrc[1];
            const half8_t* vsrc = (const half8_t*)(vt + ((size_t)bh * HD_ + srow) * VTW + m0 + scol);
            *(half8_t*)&Vl[srow][scol]     = vsrc[0];
            *(half8_t*)&Vl[srow][scol + 8] = vsrc[1];
            const int gn = (n0 + srow) < N_ ? (n0 + srow) : N_ - 1;
            const half8_t* bsrc = (const half8_t*)(posh + ((size_t)h * N_ + gn) * POSW + m0 + scol);
            *(half8_t*)&Bl[srow][scol]     = bsrc[0];
            *(half8_t*)&Bl[srow][scol + 8] = bsrc[1];
        }
        __syncthreads();

        // ---- QK^T: 4 m-subtiles x 2 k-blocks
        f32x4 s[4];
        #pragma unroll
        for (int ms = 0; ms < 4; ++ms) {
            half8_t k0 = *(const half8_t*)&Kl[ms * 16 + lr][lg * 8];
            half8_t k1 = *(const half8_t*)&Kl[ms * 16 + lr][32 + lg * 8];
            f32x4 acc = {0.f, 0.f, 0.f, 0.f};
            acc = __builtin_amdgcn_mfma_f32_16x16x32_f16(qf0, k0, acc, 0, 0, 0);
            acc = __builtin_amdgcn_mfma_f32_16x16x32_f16(qf1, k1, acc, 0, 0, 0);
            s[ms] = acc;
        }
        // ---- bias + key-validity mask (D-layout: row=lg*4+r, col=ms*16+lr)
        #pragma unroll
        for (int ms = 0; ms < 4; ++ms) {
            const bool valid = (m0 + ms * 16 + lr) < N_;
            #pragma unroll
            for (int r = 0; r < 4; ++r) {
                float b = (float)Bl[w * 16 + lg * 4 + r][ms * 16 + lr];
                s[ms][r] = valid ? (s[ms][r] + b) : -1e30f;
            }
        }
        // ---- online softmax (row-reduce over 16 lanes in group)
        float alpha[4];
        #pragma unroll
        for (int r = 0; r < 4; ++r) {
            float v = fmaxf(fmaxf(s[0][r], s[1][r]), fmaxf(s[2][r], s[3][r]));
            v = fmaxf(v, __shfl_xor(v, 1));
            v = fmaxf(v, __shfl_xor(v, 2));
            v = fmaxf(v, __shfl_xor(v, 4));
            v = fmaxf(v, __shfl_xor(v, 8));
            float mn = fmaxf(mr[r], v);
            alpha[r] = __expf(mr[r] - mn);
            mr[r] = mn;
        }
        float psum[4] = {0.f, 0.f, 0.f, 0.f};
        #pragma unroll
        for (int ms = 0; ms < 4; ++ms) {
            #pragma unroll
            for (int r = 0; r < 4; ++r) {
                float p = __expf(s[ms][r] - mr[r]);
                psum[r] += p;
                Pl[w][lg * 4 + r][ms * 16 + lr] = (_Float16)p;
            }
        }
        #pragma unroll
        for (int r = 0; r < 4; ++r) {
            float v = psum[r];
            v += __shfl_xor(v, 1);
            v += __shfl_xor(v, 2);
            v += __shfl_xor(v, 4);
            v += __shfl_xor(v, 8);
            ls[r] = ls[r] * alpha[r] + v;
            O0[r] *= alpha[r]; O1[r] *= alpha[r];
            O2[r] *= alpha[r]; O3[r] *= alpha[r];
        }
        // ---- PV: A = P (via per-wave LDS round-trip), B = V^T rows
        const half8_t pa0 = *(const half8_t*)&Pl[w][lr][lg * 8];
        const half8_t pa1 = *(const half8_t*)&Pl[w][lr][32 + lg * 8];
        #pragma unroll
        for (int ds = 0; ds < 4; ++ds) {
            half8_t v0 = *(const half8_t*)&Vl[ds * 16 + lr][lg * 8];
            half8_t v1 = *(const half8_t*)&Vl[ds * 16 + lr][32 + lg * 8];
            f32x4& Od = (ds == 0 ? O0 : ds == 1 ? O1 : ds == 2 ? O2 : O3);
            Od = __builtin_amdgcn_mfma_f32_16x16x32_f16(pa0, v0, Od, 0, 0, 0);
            Od = __builtin_amdgcn_mfma_f32_16x16x32_f16(pa1, v1, Od, 0, 0, 0);
        }
        __syncthreads();
    }

    // ---- epilogue: rows n0 + w*16 + lg*4 + r, col d = ds*16 + lr
    const int bb = bh / H_;
    #pragma unroll
    for (int r = 0; r < 4; ++r) {
        const int n = n0 + w * 16 + lg * 4 + r;
        if (n >= N_) continue;
        const float inv = 1.f / ls[r];
        _Float16* dst = aoh + ((size_t)(bb * N_ + n)) * C_ + h * HD_;
        dst[0 * 16 + lr] = (_Float16)(O0[r] * inv);
        dst[1 * 16 + lr] = (_Float16)(O1[r] * inv);
        dst[2 * 16 + lr] = (_Float16)(O2[r] * inv);
        dst[3 * 16 + lr] = (_Float16)(O3[r] * inv);
    }
}

// ---------------------------------------------------------------------------
// K4: out = aoh @ proj_w^T + proj_b   (fp32 out)
// ---------------------------------------------------------------------------
__global__ __launch_bounds__(256) void proj_gemm(
    const __half* __restrict__ a, const float* __restrict__ w,
    const float* __restrict__ bias, float* __restrict__ out)
{
    __shared__ float As[16][136];
    __shared__ float Bs[16][136];
    const int t  = threadIdx.x;
    const int m0 = blockIdx.x * 128;
    const int n0 = blockIdx.y * 128;
    const int tr = t >> 4, tc = t & 15;
    const int i0 = tr * 8, j0 = tc * 8;

    float acc[8][8];
    #pragma unroll
    for (int i = 0; i < 8; ++i)
        #pragma unroll
        for (int j = 0; j < 8; ++j) acc[i][j] = 0.f;

    for (int k0 = 0; k0 < 768; k0 += 16) {
        {
            int row = t >> 1, cg = (t & 1) * 8;
            int gm = m0 + row;
            if (gm < M_) {
                Half8 a8 = *(const Half8*)&a[(size_t)gm * 768 + k0 + cg];
                #pragma unroll
                for (int e = 0; e < 8; ++e) As[cg + e][row] = __half2float(a8.h[e]);
            } else {
                #pragma unroll
                for (int e = 0; e < 8; ++e) As[cg + e][row] = 0.f;
            }
        }
        #pragma unroll
        for (int l = 0; l < 2; ++l) {
            int f = t + l * 256;
            int row = f >> 2, c4 = (f & 3) * 4;
            float4 u = *(const float4*)&w[(n0 + row) * 768 + k0 + c4];
            Bs[c4+0][row] = u.x; Bs[c4+1][row] = u.y;
            Bs[c4+2][row] = u.z; Bs[c4+3][row] = u.w;
        }
        __syncthreads();
        #pragma unroll
        for (int k = 0; k < 16; ++k) {
            float av[8], bv[8];
            *(float4*)&av[0] = *(const float4*)&As[k][i0];
            *(float4*)&av[4] = *(const float4*)&As[k][i0 + 4];
            *(float4*)&bv[0] = *(const float4*)&Bs[k][j0];
            *(float4*)&bv[4] = *(const float4*)&Bs[k][j0 + 4];
            #pragma unroll
            for (int i = 0; i < 8; ++i)
                #pragma unroll
                for (int j = 0; j < 8; ++j)
                    acc[i][j] = fmaf(av[i], bv[j], acc[i][j]);
        }
        __syncthreads();
    }

    #pragma unroll
    for (int i = 0; i < 8; ++i) {
        int m = m0 + i0 + i;
        if (m >= M_) continue;
        #pragma unroll
        for (int j = 0; j < 8; ++j) {
            int o = n0 + j0 + j;
            out[(size_t)m * 768 + o] = acc[i][j] + bias[o];
        }
    }
}

// ---------------------------------------------------------------------------
extern "C" void kernel_launch(void* const* d_in, const int* in_sizes, int n_in,
                              void* d_out, int out_size, void* d_ws, size_t ws_size,
                              hipStream_t stream)
{
    const float* x     = (const float*)d_in[0];
    const float* qkv_w = (const float*)d_in[1];
    const float* pe    = (const float*)d_in[2];
    const float* pw    = (const float*)d_in[3];
    const float* pjw   = (const float*)d_in[4];
    const float* pjb   = (const float*)d_in[5];
    float* out = (float*)d_out;

    __half* wsh  = (__half*)d_ws;
    __half* qh   = wsh + OFF_Q;
    __half* kh   = wsh + OFF_K;
    __half* vth  = wsh + OFF_VT;
    __half* posh = wsh + OFF_POS;
    __half* aoh  = wsh + OFF_AO;

    qkv_gemm<<<dim3(99, 18), 256, 0, stream>>>(x, qkv_w, qh, kh, vth);
    pos_kernel<<<dim3((N_ * N_ + 255) / 256), 256, 0, stream>>>(pe, pw, posh);
    attn_mfma<<<dim3(13, 192), 256, 0, stream>>>(
        (const _Float16*)qh, (const _Float16*)kh, (const _Float16*)vth,
        (const _Float16*)posh, (_Float16*)aoh);
    proj_gemm<<<dim3(99, 6), 256, 0, stream>>>(aoh, pjw, pjb, out);
}

// Round 3
// 312.443 us; speedup vs baseline: 5.1347x; 3.0845x over previous
//
#include <hip/hip_runtime.h>
#include <hip/hip_fp16.h>

#define B_ 16
#define N_ 785
#define C_ 768
#define H_ 12
#define HD_ 64
#define P_ 48
#define M_ (B_*N_)      // 12560
#define MPAD 12672      // 99 * 128
#define POSW 800        // padded row stride (halves) for pos bias
#define VTW  800        // padded row stride (halves) for V^T
#define SCALE 0.125f    // hd^-0.5

// ws layout (fp16 element offsets)
#define OFF_Q   0                         //  9,646,080
#define OFF_K   9646080                   //  9,646,080
#define OFF_VT  19292160                  //  9,830,400 (16*12*64*800)
#define OFF_POS 29122560                  //  7,536,000 (12*785*800)
#define OFF_XF  36658560                  //  9,732,096 (12672*768) — x-f16, later reused as attn-out
#define OFF_AO  OFF_XF                    //  alias: x dead after qkv_gemm
#define OFF_WQ  46390656                  //  1,769,472 (2304*768)
#define OFF_WP  48160128                  //    589,824 (768*768)   end: 48,749,952 halves = 97.5 MB

struct __align__(16) Half8 { __half h[8]; };
typedef _Float16 half8_t __attribute__((ext_vector_type(8)));
typedef _Float16 half4_t __attribute__((ext_vector_type(4)));
typedef float f32x4 __attribute__((ext_vector_type(4)));

__device__ __forceinline__ void gl16(const void* g, void* l) {
    __builtin_amdgcn_global_load_lds(
        (const __attribute__((address_space(1))) void*)g,
        (__attribute__((address_space(3))) void*)l, 16, 0, 0);
}

// ---------------------------------------------------------------------------
// K0: fp32 -> fp16 convert of x, qkv_w, proj_w (vectorized, exact-cover grid)
// ---------------------------------------------------------------------------
#define NX4 2411520     // 9,646,080 / 4
#define NQ4 442368      // 1,769,472 / 4
#define NP4 147456      //   589,824 / 4
#define NTOT4 (NX4+NQ4+NP4)   // 3,001,344 = 11724 * 256

__global__ __launch_bounds__(256) void convert_f16(
    const float* __restrict__ x, const float* __restrict__ wq,
    const float* __restrict__ wp, _Float16* __restrict__ xo,
    _Float16* __restrict__ wqo, _Float16* __restrict__ wpo)
{
    int i = blockIdx.x * 256 + threadIdx.x;
    const float4* s; _Float16* d; int o;
    if (i < NX4)            { s = (const float4*)x;  d = xo;  o = i; }
    else if (i < NX4 + NQ4) { s = (const float4*)wq; d = wqo; o = i - NX4; }
    else                    { s = (const float4*)wp; d = wpo; o = i - NX4 - NQ4; }
    float4 v = s[o];
    half4_t h = { (_Float16)v.x, (_Float16)v.y, (_Float16)v.z, (_Float16)v.w };
    *(half4_t*)&d[o * 4] = h;
}

// ---------------------------------------------------------------------------
// K1: qkv MFMA GEMM: C[m][n] = sum_k A[m][k] * W[n][k]; scatter q/k/v^T
//     128x128 tile, BK=32, 4 waves (2x2), 4x4 16x16x32 frags per wave.
// ---------------------------------------------------------------------------
__global__ __launch_bounds__(256) void qkv_gemm_mfma(
    const _Float16* __restrict__ A, const _Float16* __restrict__ Bw,
    __half* __restrict__ qh, __half* __restrict__ kh, __half* __restrict__ vth)
{
    __shared__ _Float16 Asl[128 * 32];
    __shared__ _Float16 Bsl[128 * 32];

    const int t  = threadIdx.x;
    const int w  = t >> 6;
    const int l  = t & 63;
    const int lr = l & 15;
    const int lg = l >> 4;
    const int wm = (w >> 1) * 64;
    const int wn = (w & 1) * 64;
    const int n0 = blockIdx.x * 128;     // n fastest: A-rows shared across adjacent blocks
    const int m0 = blockIdx.y * 128;

    // staging addresses (row-major [128][32] halves LDS; linear dest for global_load_lds)
    const int f1 = t + 256;
    const int ar0 = t >> 2,  ac0 = (t & 3) * 8;
    const int ar1 = f1 >> 2, ac1 = (f1 & 3) * 8;
    const _Float16* Ag0 = A  + (size_t)(m0 + ar0) * 768 + ac0;
    const _Float16* Ag1 = A  + (size_t)(m0 + ar1) * 768 + ac1;
    const _Float16* Bg0 = Bw + (size_t)(n0 + ar0) * 768 + ac0;
    const _Float16* Bg1 = Bw + (size_t)(n0 + ar1) * 768 + ac1;
    _Float16* Al0 = &Asl[t * 8];
    _Float16* Al1 = &Asl[f1 * 8];
    _Float16* Bl0 = &Bsl[t * 8];
    _Float16* Bl1 = &Bsl[f1 * 8];

    f32x4 acc[4][4];
    #pragma unroll
    for (int i = 0; i < 4; ++i)
        #pragma unroll
        for (int j = 0; j < 4; ++j) acc[i][j] = (f32x4){0.f, 0.f, 0.f, 0.f};

    for (int k0 = 0; k0 < 768; k0 += 32) {
        gl16(Ag0 + k0, Al0); gl16(Ag1 + k0, Al1);
        gl16(Bg0 + k0, Bl0); gl16(Bg1 + k0, Bl1);
        __syncthreads();
        half8_t af[4], bf[4];
        #pragma unroll
        for (int i = 0; i < 4; ++i)
            af[i] = *(const half8_t*)&Asl[(wm + i * 16 + lr) * 32 + lg * 8];
        #pragma unroll
        for (int j = 0; j < 4; ++j)
            bf[j] = *(const half8_t*)&Bsl[(wn + j * 16 + lr) * 32 + lg * 8];
        #pragma unroll
        for (int i = 0; i < 4; ++i)
            #pragma unroll
            for (int j = 0; j < 4; ++j)
                acc[i][j] = __builtin_amdgcn_mfma_f32_16x16x32_f16(af[i], bf[j], acc[i][j], 0, 0, 0);
        __syncthreads();
    }

    // epilogue: n-block maps uniformly to q/k/v (6 blocks each)
    const int tsel  = blockIdx.x / 6;          // 0=q 1=k 2=v
    const int nbase = n0 - tsel * 768;
    #pragma unroll
    for (int i = 0; i < 4; ++i) {
        #pragma unroll
        for (int r = 0; r < 4; ++r) {
            const int m = m0 + wm + i * 16 + lg * 4 + r;
            if (m >= M_) continue;
            const int bb = m / N_, nn = m - bb * N_;
            #pragma unroll
            for (int j = 0; j < 4; ++j) {
                const int nsec = nbase + wn + j * 16 + lr;
                const int hh = nsec >> 6, dd = nsec & 63;
                const float v = acc[i][j][r];
                if (tsel == 0)
                    qh[((size_t)(bb * H_ + hh) * N_ + nn) * HD_ + dd] = __float2half(v * SCALE);
                else if (tsel == 1)
                    kh[((size_t)(bb * H_ + hh) * N_ + nn) * HD_ + dd] = __float2half(v);
                else
                    vth[((size_t)(bb * H_ + hh) * HD_ + dd) * VTW + nn] = __float2half(v);
            }
        }
    }
}

// ---------------------------------------------------------------------------
// K2: pos bias: posh[h][n][m] = SCALE * sum_p pos_emb[n][m][p] * pw[h][p]
// ---------------------------------------------------------------------------
__global__ __launch_bounds__(256) void pos_kernel(
    const float* __restrict__ pe, const float* __restrict__ pw,
    __half* __restrict__ posh)
{
    __shared__ float W[H_][P_];
    const int t = threadIdx.x;
    for (int i = t; i < H_ * P_; i += 256) W[i / P_][i % P_] = pw[i];
    __syncthreads();
    int nm = blockIdx.x * 256 + t;
    if (nm >= N_ * N_) return;
    float e[48];
    const float4* src = (const float4*)(pe + (size_t)nm * 48);
    #pragma unroll
    for (int i = 0; i < 12; ++i) {
        float4 v = src[i];
        e[4*i] = v.x; e[4*i+1] = v.y; e[4*i+2] = v.z; e[4*i+3] = v.w;
    }
    int n = nm / N_, m = nm - n * N_;
    #pragma unroll
    for (int hh = 0; hh < H_; ++hh) {
        float s = 0.f;
        #pragma unroll
        for (int p = 0; p < 48; ++p) s = fmaf(e[p], W[hh][p], s);
        posh[((size_t)hh * N_ + n) * POSW + m] = __float2half(s * SCALE);
    }
}

// ---------------------------------------------------------------------------
// K3: MFMA flash attention. Block = (qtile of 64, bh). 4 waves x 16 q-rows.
// ---------------------------------------------------------------------------
__global__ __launch_bounds__(256) void attn_mfma(
    const _Float16* __restrict__ qh, const _Float16* __restrict__ kh,
    const _Float16* __restrict__ vt, const _Float16* __restrict__ posh,
    _Float16* __restrict__ aoh)
{
    __shared__ _Float16 Kl[64][72];          // keys  [m][d]
    __shared__ _Float16 Vl[64][72];          // V^T   [d][m]
    __shared__ _Float16 Bl[64][72];          // bias  [qrow][m]
    __shared__ _Float16 Pl[4][16][72];       // per-wave P [qrow][m]

    const int t  = threadIdx.x;
    const int w  = t >> 6;                   // wave 0..3
    const int l  = t & 63;
    const int lr = l & 15;                   // fragment row/col
    const int lg = l >> 4;                   // k-group 0..3
    const int bh = blockIdx.y;
    const int h  = bh % H_;
    const int n0 = blockIdx.x * 64;

    const int qrow = n0 + w * 16 + lr;
    const int qrc  = qrow < N_ ? qrow : N_ - 1;
    const half8_t qf0 = *(const half8_t*)(qh + ((size_t)bh * N_ + qrc) * HD_ + lg * 8);
    const half8_t qf1 = *(const half8_t*)(qh + ((size_t)bh * N_ + qrc) * HD_ + 32 + lg * 8);

    f32x4 O0 = {0.f,0.f,0.f,0.f}, O1 = O0, O2 = O0, O3 = O0;
    float mr[4] = {-1e30f, -1e30f, -1e30f, -1e30f};
    float ls[4] = {0.f, 0.f, 0.f, 0.f};

    const int srow = t >> 2;
    const int scol = (t & 3) * 16;

    for (int c = 0; c < 13; ++c) {
        const int m0 = c * 64;
        {
            const int gm = (m0 + srow) < N_ ? (m0 + srow) : N_ - 1;
            const half8_t* ksrc = (const half8_t*)(kh + ((size_t)bh * N_ + gm) * HD_ + scol);
            *(half8_t*)&Kl[srow][scol]     = ksrc[0];
            *(half8_t*)&Kl[srow][scol + 8] = ksrc[1];
            const half8_t* vsrc = (const half8_t*)(vt + ((size_t)bh * HD_ + srow) * VTW + m0 + scol);
            *(half8_t*)&Vl[srow][scol]     = vsrc[0];
            *(half8_t*)&Vl[srow][scol + 8] = vsrc[1];
            const int gn = (n0 + srow) < N_ ? (n0 + srow) : N_ - 1;
            const half8_t* bsrc = (const half8_t*)(posh + ((size_t)h * N_ + gn) * POSW + m0 + scol);
            *(half8_t*)&Bl[srow][scol]     = bsrc[0];
            *(half8_t*)&Bl[srow][scol + 8] = bsrc[1];
        }
        __syncthreads();

        f32x4 s[4];
        #pragma unroll
        for (int ms = 0; ms < 4; ++ms) {
            half8_t k0 = *(const half8_t*)&Kl[ms * 16 + lr][lg * 8];
            half8_t k1 = *(const half8_t*)&Kl[ms * 16 + lr][32 + lg * 8];
            f32x4 acc = {0.f, 0.f, 0.f, 0.f};
            acc = __builtin_amdgcn_mfma_f32_16x16x32_f16(qf0, k0, acc, 0, 0, 0);
            acc = __builtin_amdgcn_mfma_f32_16x16x32_f16(qf1, k1, acc, 0, 0, 0);
            s[ms] = acc;
        }
        #pragma unroll
        for (int ms = 0; ms < 4; ++ms) {
            const bool valid = (m0 + ms * 16 + lr) < N_;
            #pragma unroll
            for (int r = 0; r < 4; ++r) {
                float b = (float)Bl[w * 16 + lg * 4 + r][ms * 16 + lr];
                s[ms][r] = valid ? (s[ms][r] + b) : -1e30f;
            }
        }
        float alpha[4];
        #pragma unroll
        for (int r = 0; r < 4; ++r) {
            float v = fmaxf(fmaxf(s[0][r], s[1][r]), fmaxf(s[2][r], s[3][r]));
            v = fmaxf(v, __shfl_xor(v, 1));
            v = fmaxf(v, __shfl_xor(v, 2));
            v = fmaxf(v, __shfl_xor(v, 4));
            v = fmaxf(v, __shfl_xor(v, 8));
            float mn = fmaxf(mr[r], v);
            alpha[r] = __expf(mr[r] - mn);
            mr[r] = mn;
        }
        float psum[4] = {0.f, 0.f, 0.f, 0.f};
        #pragma unroll
        for (int ms = 0; ms < 4; ++ms) {
            #pragma unroll
            for (int r = 0; r < 4; ++r) {
                float p = __expf(s[ms][r] - mr[r]);
                psum[r] += p;
                Pl[w][lg * 4 + r][ms * 16 + lr] = (_Float16)p;
            }
        }
        #pragma unroll
        for (int r = 0; r < 4; ++r) {
            float v = psum[r];
            v += __shfl_xor(v, 1);
            v += __shfl_xor(v, 2);
            v += __shfl_xor(v, 4);
            v += __shfl_xor(v, 8);
            ls[r] = ls[r] * alpha[r] + v;
            O0[r] *= alpha[r]; O1[r] *= alpha[r];
            O2[r] *= alpha[r]; O3[r] *= alpha[r];
        }
        const half8_t pa0 = *(const half8_t*)&Pl[w][lr][lg * 8];
        const half8_t pa1 = *(const half8_t*)&Pl[w][lr][32 + lg * 8];
        #pragma unroll
        for (int ds = 0; ds < 4; ++ds) {
            half8_t v0 = *(const half8_t*)&Vl[ds * 16 + lr][lg * 8];
            half8_t v1 = *(const half8_t*)&Vl[ds * 16 + lr][32 + lg * 8];
            f32x4& Od = (ds == 0 ? O0 : ds == 1 ? O1 : ds == 2 ? O2 : O3);
            Od = __builtin_amdgcn_mfma_f32_16x16x32_f16(pa0, v0, Od, 0, 0, 0);
            Od = __builtin_amdgcn_mfma_f32_16x16x32_f16(pa1, v1, Od, 0, 0, 0);
        }
        __syncthreads();
    }

    const int bb = bh / H_;
    #pragma unroll
    for (int r = 0; r < 4; ++r) {
        const int n = n0 + w * 16 + lg * 4 + r;
        if (n >= N_) continue;
        const float inv = 1.f / ls[r];
        _Float16* dst = aoh + ((size_t)(bb * N_ + n)) * C_ + h * HD_;
        dst[0 * 16 + lr] = (_Float16)(O0[r] * inv);
        dst[1 * 16 + lr] = (_Float16)(O1[r] * inv);
        dst[2 * 16 + lr] = (_Float16)(O2[r] * inv);
        dst[3 * 16 + lr] = (_Float16)(O3[r] * inv);
    }
}

// ---------------------------------------------------------------------------
// K4: proj MFMA GEMM: out[m][n] = sum_k AO[m][k] * Wp[n][k] + bias[n] (fp32)
// ---------------------------------------------------------------------------
__global__ __launch_bounds__(256) void proj_gemm_mfma(
    const _Float16* __restrict__ A, const _Float16* __restrict__ Bw,
    const float* __restrict__ bias, float* __restrict__ out)
{
    __shared__ _Float16 Asl[128 * 32];
    __shared__ _Float16 Bsl[128 * 32];

    const int t  = threadIdx.x;
    const int w  = t >> 6;
    const int l  = t & 63;
    const int lr = l & 15;
    const int lg = l >> 4;
    const int wm = (w >> 1) * 64;
    const int wn = (w & 1) * 64;
    const int n0 = blockIdx.x * 128;
    const int m0 = blockIdx.y * 128;

    const int f1 = t + 256;
    const int ar0 = t >> 2,  ac0 = (t & 3) * 8;
    const int ar1 = f1 >> 2, ac1 = (f1 & 3) * 8;
    const _Float16* Ag0 = A  + (size_t)(m0 + ar0) * 768 + ac0;
    const _Float16* Ag1 = A  + (size_t)(m0 + ar1) * 768 + ac1;
    const _Float16* Bg0 = Bw + (size_t)(n0 + ar0) * 768 + ac0;
    const _Float16* Bg1 = Bw + (size_t)(n0 + ar1) * 768 + ac1;
    _Float16* Al0 = &Asl[t * 8];
    _Float16* Al1 = &Asl[f1 * 8];
    _Float16* Bl0 = &Bsl[t * 8];
    _Float16* Bl1 = &Bsl[f1 * 8];

    f32x4 acc[4][4];
    #pragma unroll
    for (int i = 0; i < 4; ++i)
        #pragma unroll
        for (int j = 0; j < 4; ++j) acc[i][j] = (f32x4){0.f, 0.f, 0.f, 0.f};

    for (int k0 = 0; k0 < 768; k0 += 32) {
        gl16(Ag0 + k0, Al0); gl16(Ag1 + k0, Al1);
        gl16(Bg0 + k0, Bl0); gl16(Bg1 + k0, Bl1);
        __syncthreads();
        half8_t af[4], bf[4];
        #pragma unroll
        for (int i = 0; i < 4; ++i)
            af[i] = *(const half8_t*)&Asl[(wm + i * 16 + lr) * 32 + lg * 8];
        #pragma unroll
        for (int j = 0; j < 4; ++j)
            bf[j] = *(const half8_t*)&Bsl[(wn + j * 16 + lr) * 32 + lg * 8];
        #pragma unroll
        for (int i = 0; i < 4; ++i)
            #pragma unroll
            for (int j = 0; j < 4; ++j)
                acc[i][j] = __builtin_amdgcn_mfma_f32_16x16x32_f16(af[i], bf[j], acc[i][j], 0, 0, 0);
        __syncthreads();
    }

    float bj[4];
    #pragma unroll
    for (int j = 0; j < 4; ++j) bj[j] = bias[n0 + wn + j * 16 + lr];
    #pragma unroll
    for (int i = 0; i < 4; ++i) {
        #pragma unroll
        for (int r = 0; r < 4; ++r) {
            const int m = m0 + wm + i * 16 + lg * 4 + r;
            if (m >= M_) continue;
            #pragma unroll
            for (int j = 0; j < 4; ++j) {
                const int n = n0 + wn + j * 16 + lr;
                out[(size_t)m * 768 + n] = acc[i][j][r] + bj[j];
            }
        }
    }
}

// ---------------------------------------------------------------------------
extern "C" void kernel_launch(void* const* d_in, const int* in_sizes, int n_in,
                              void* d_out, int out_size, void* d_ws, size_t ws_size,
                              hipStream_t stream)
{
    const float* x     = (const float*)d_in[0];
    const float* qkv_w = (const float*)d_in[1];
    const float* pe    = (const float*)d_in[2];
    const float* pw    = (const float*)d_in[3];
    const float* pjw   = (const float*)d_in[4];
    const float* pjb   = (const float*)d_in[5];
    float* out = (float*)d_out;

    _Float16* wsh  = (_Float16*)d_ws;
    _Float16* qh   = wsh + OFF_Q;
    _Float16* kh   = wsh + OFF_K;
    _Float16* vth  = wsh + OFF_VT;
    _Float16* posh = wsh + OFF_POS;
    _Float16* xf   = wsh + OFF_XF;
    _Float16* aoh  = wsh + OFF_AO;       // aliases xf (x dead after qkv_gemm)
    _Float16* wqf  = wsh + OFF_WQ;
    _Float16* wpf  = wsh + OFF_WP;

    convert_f16<<<dim3(NTOT4 / 256), 256, 0, stream>>>(x, qkv_w, pjw, xf, wqf, wpf);
    qkv_gemm_mfma<<<dim3(18, 99), 256, 0, stream>>>(
        xf, wqf, (__half*)qh, (__half*)kh, (__half*)vth);
    pos_kernel<<<dim3((N_ * N_ + 255) / 256), 256, 0, stream>>>(pe, pw, (__half*)posh);
    attn_mfma<<<dim3(13, 192), 256, 0, stream>>>(qh, kh, vth, posh, aoh);
    proj_gemm_mfma<<<dim3(6, 99), 256, 0, stream>>>(aoh, wpf, pjb, out);
}

// Round 5
// 290.642 us; speedup vs baseline: 5.5199x; 1.0750x over previous
//
#include <hip/hip_runtime.h>
#include <hip/hip_fp16.h>

#define B_ 16
#define N_ 785
#define C_ 768
#define H_ 12
#define HD_ 64
#define P_ 48
#define M_ (B_*N_)      // 12560
#define POSW 832        // padded row stride (halves) for pos bias (13*64)
#define VTW  832        // padded row stride (halves) for V^T
#define SLOG2E 0.1803368801111244f   // (hd^-0.5) * log2(e)

// ws layout (fp16 element offsets)
#define OFF_Q   0                    //  9,646,080
#define OFF_K   9646080              //  9,646,080
#define OFF_VT  19292160             // 10,223,616 (16*12*64*832)
#define OFF_POS 29515776             //  7,837,440 (12*785*832)
#define OFF_XF  37353216             //  9,732,096 (12672*768) — x-f16, later attn-out
#define OFF_AO  OFF_XF               //  alias: x dead after qkv_gemm
#define OFF_WQ  47085312             //  1,769,472 (2304*768)
#define OFF_WP  48854784             //    589,824 (768*768)  end: 49,444,608 halves

struct __align__(16) Half8 { __half h[8]; };
typedef _Float16 half8_t __attribute__((ext_vector_type(8)));
typedef _Float16 half4_t __attribute__((ext_vector_type(4)));
typedef float f32x4 __attribute__((ext_vector_type(4)));

__device__ __forceinline__ void gl16(const void* g, void* l) {
    __builtin_amdgcn_global_load_lds(
        (const __attribute__((address_space(1))) void*)g,
        (__attribute__((address_space(3))) void*)l, 16, 0, 0);
}

// ---------------------------------------------------------------------------
// K0: fp32 -> fp16 convert of x, qkv_w, proj_w
// ---------------------------------------------------------------------------
#define NX4 2411520
#define NQ4 442368
#define NP4 147456
#define NTOT4 (NX4+NQ4+NP4)   // 3,001,344 = 11724 * 256

__global__ __launch_bounds__(256) void convert_f16(
    const float* __restrict__ x, const float* __restrict__ wq,
    const float* __restrict__ wp, _Float16* __restrict__ xo,
    _Float16* __restrict__ wqo, _Float16* __restrict__ wpo)
{
    int i = blockIdx.x * 256 + threadIdx.x;
    const float4* s; _Float16* d; int o;
    if (i < NX4)            { s = (const float4*)x;  d = xo;  o = i; }
    else if (i < NX4 + NQ4) { s = (const float4*)wq; d = wqo; o = i - NX4; }
    else                    { s = (const float4*)wp; d = wpo; o = i - NX4 - NQ4; }
    float4 v = s[o];
    half4_t h = { (_Float16)v.x, (_Float16)v.y, (_Float16)v.z, (_Float16)v.w };
    *(half4_t*)&d[o * 4] = h;
}

// ---------------------------------------------------------------------------
// K1: qkv MFMA GEMM; scatter q (pre-scaled by SCALE*log2e) / k / v^T
// ---------------------------------------------------------------------------
__global__ __launch_bounds__(256) void qkv_gemm_mfma(
    const _Float16* __restrict__ A, const _Float16* __restrict__ Bw,
    __half* __restrict__ qh, __half* __restrict__ kh, __half* __restrict__ vth)
{
    __shared__ _Float16 Asl[128 * 32];
    __shared__ _Float16 Bsl[128 * 32];

    const int t  = threadIdx.x;
    const int w  = t >> 6;
    const int l  = t & 63;
    const int lr = l & 15;
    const int lg = l >> 4;
    const int wm = (w >> 1) * 64;
    const int wn = (w & 1) * 64;
    const int n0 = blockIdx.x * 128;
    const int m0 = blockIdx.y * 128;

    const int f1 = t + 256;
    const int ar0 = t >> 2,  ac0 = (t & 3) * 8;
    const int ar1 = f1 >> 2, ac1 = (f1 & 3) * 8;
    const _Float16* Ag0 = A  + (size_t)(m0 + ar0) * 768 + ac0;
    const _Float16* Ag1 = A  + (size_t)(m0 + ar1) * 768 + ac1;
    const _Float16* Bg0 = Bw + (size_t)(n0 + ar0) * 768 + ac0;
    const _Float16* Bg1 = Bw + (size_t)(n0 + ar1) * 768 + ac1;
    _Float16* Al0 = &Asl[t * 8];
    _Float16* Al1 = &Asl[f1 * 8];
    _Float16* Bl0 = &Bsl[t * 8];
    _Float16* Bl1 = &Bsl[f1 * 8];

    f32x4 acc[4][4];
    #pragma unroll
    for (int i = 0; i < 4; ++i)
        #pragma unroll
        for (int j = 0; j < 4; ++j) acc[i][j] = (f32x4){0.f, 0.f, 0.f, 0.f};

    for (int k0 = 0; k0 < 768; k0 += 32) {
        gl16(Ag0 + k0, Al0); gl16(Ag1 + k0, Al1);
        gl16(Bg0 + k0, Bl0); gl16(Bg1 + k0, Bl1);
        __syncthreads();
        half8_t af[4], bf[4];
        #pragma unroll
        for (int i = 0; i < 4; ++i)
            af[i] = *(const half8_t*)&Asl[(wm + i * 16 + lr) * 32 + lg * 8];
        #pragma unroll
        for (int j = 0; j < 4; ++j)
            bf[j] = *(const half8_t*)&Bsl[(wn + j * 16 + lr) * 32 + lg * 8];
        __builtin_amdgcn_s_setprio(1);
        #pragma unroll
        for (int i = 0; i < 4; ++i)
            #pragma unroll
            for (int j = 0; j < 4; ++j)
                acc[i][j] = __builtin_amdgcn_mfma_f32_16x16x32_f16(af[i], bf[j], acc[i][j], 0, 0, 0);
        __builtin_amdgcn_s_setprio(0);
        __syncthreads();
    }

    const int tsel  = blockIdx.x / 6;          // 0=q 1=k 2=v
    const int nbase = n0 - tsel * 768;
    #pragma unroll
    for (int i = 0; i < 4; ++i) {
        #pragma unroll
        for (int r = 0; r < 4; ++r) {
            const int m = m0 + wm + i * 16 + lg * 4 + r;
            if (m >= M_) continue;
            const int bb = m / N_, nn = m - bb * N_;
            #pragma unroll
            for (int j = 0; j < 4; ++j) {
                const int nsec = nbase + wn + j * 16 + lr;
                const int hh = nsec >> 6, dd = nsec & 63;
                const float v = acc[i][j][r];
                if (tsel == 0)
                    qh[((size_t)(bb * H_ + hh) * N_ + nn) * HD_ + dd] = __float2half(v * SLOG2E);
                else if (tsel == 1)
                    kh[((size_t)(bb * H_ + hh) * N_ + nn) * HD_ + dd] = __float2half(v);
                else
                    vth[((size_t)(bb * H_ + hh) * HD_ + dd) * VTW + nn] = __float2half(v);
            }
        }
    }
}

// ---------------------------------------------------------------------------
// K2: pos bias (scaled by SCALE*log2e): posh[h][n][m]
// ---------------------------------------------------------------------------
__global__ __launch_bounds__(256) void pos_kernel(
    const float* __restrict__ pe, const float* __restrict__ pw,
    __half* __restrict__ posh)
{
    __shared__ float W[H_][P_];
    const int t = threadIdx.x;
    for (int i = t; i < H_ * P_; i += 256) W[i / P_][i % P_] = pw[i];
    __syncthreads();
    int nm = blockIdx.x * 256 + t;
    if (nm >= N_ * N_) return;
    float e[48];
    const float4* src = (const float4*)(pe + (size_t)nm * 48);
    #pragma unroll
    for (int i = 0; i < 12; ++i) {
        float4 v = src[i];
        e[4*i] = v.x; e[4*i+1] = v.y; e[4*i+2] = v.z; e[4*i+3] = v.w;
    }
    int n = nm / N_, m = nm - n * N_;
    #pragma unroll
    for (int hh = 0; hh < H_; ++hh) {
        float s = 0.f;
        #pragma unroll
        for (int p = 0; p < 48; ++p) s = fmaf(e[p], W[hh][p], s);
        posh[((size_t)hh * N_ + n) * POSW + m] = __float2half(s * SLOG2E);
    }
}

// ---------------------------------------------------------------------------
// K3: MFMA flash attention, swapped-QK^T (q-row lane-local softmax),
//     lane-local P via V column permutation, exp2 domain, defer-max,
//     register prefetch of next K/V/bias chunk.
// ---------------------------------------------------------------------------
__global__ __launch_bounds__(256) void attn_mfma(
    const _Float16* __restrict__ qh, const _Float16* __restrict__ kh,
    const _Float16* __restrict__ vt, const _Float16* __restrict__ posh,
    _Float16* __restrict__ aoh)
{
    __shared__ _Float16 Kl[64][72];          // keys  [m][d]
    __shared__ _Float16 Vl[64][72];          // V^T   [d][m]
    __shared__ _Float16 Bl[64][72];          // bias  [qrow][m]

    const int t  = threadIdx.x;
    const int w  = t >> 6;                   // wave 0..3
    const int l  = t & 63;
    const int lr = l & 15;
    const int lg = l >> 4;

    // grid: g = ((qt*12 + h) << 4) | b  — 16 batch-blocks sharing a bias tile
    // are dispatch-adjacent for L2 reuse.
    const int g   = blockIdx.x;
    const int b   = g & 15;
    const int grp = g >> 4;
    const int qt  = grp / 12;
    const int h   = grp - qt * 12;
    const int bh  = b * H_ + h;
    const int n0  = qt * 64;

    // Q fragments (pre-scaled by SCALE*log2e in K1); clamped row for tail
    const int qrow = n0 + w * 16 + lr;
    const int qrc  = qrow < N_ ? qrow : N_ - 1;
    const _Float16* qbase = qh + ((size_t)bh * N_ + qrc) * HD_;
    const half8_t qf0 = *(const half8_t*)(qbase + lg * 8);
    const half8_t qf1 = *(const half8_t*)(qbase + 32 + lg * 8);

    f32x4 O0 = {0.f,0.f,0.f,0.f}, O1 = O0, O2 = O0, O3 = O0;
    float m_run = -1e30f;        // per-lane: running max of q-row lr (log2 dom)
    float l_run = 0.f;           // per-lane: running denom of q-row lr

    const int srow = t >> 2;
    const int scol = (t & 3) * 16;
    const _Float16* kRow = kh + ((size_t)bh * N_) * HD_ + scol;
    const _Float16* vRow = vt + ((size_t)bh * HD_ + srow) * VTW + scol;
    const _Float16* bRow = posh + ((size_t)h * N_ + (n0 + srow < N_ ? n0 + srow : N_ - 1)) * POSW + scol;

    // prefetch chunk 0
    half8_t rk0, rk1, rv0, rv1, rb0, rb1;
    {
        const int gm = srow < N_ ? srow : N_ - 1;
        const half8_t* ks = (const half8_t*)(kRow + (size_t)gm * HD_);
        rk0 = ks[0]; rk1 = ks[1];
        const half8_t* vs = (const half8_t*)vRow;
        rv0 = vs[0]; rv1 = vs[1];
        const half8_t* bs = (const half8_t*)bRow;
        rb0 = bs[0]; rb1 = bs[1];
    }

    for (int c = 0; c < 13; ++c) {
        // commit prefetched chunk to LDS
        *(half8_t*)&Kl[srow][scol]     = rk0;
        *(half8_t*)&Kl[srow][scol + 8] = rk1;
        *(half8_t*)&Vl[srow][scol]     = rv0;
        *(half8_t*)&Vl[srow][scol + 8] = rv1;
        *(half8_t*)&Bl[srow][scol]     = rb0;
        *(half8_t*)&Bl[srow][scol + 8] = rb1;
        __syncthreads();

        // issue next chunk's loads (latency hidden under compute)
        if (c < 12) {
            const int m0n = (c + 1) * 64;
            const int gm  = (m0n + srow) < N_ ? (m0n + srow) : N_ - 1;
            const half8_t* ks = (const half8_t*)(kRow + (size_t)gm * HD_);
            rk0 = ks[0]; rk1 = ks[1];
            const half8_t* vs = (const half8_t*)(vRow + m0n);
            rv0 = vs[0]; rv1 = vs[1];
            const half8_t* bs = (const half8_t*)(bRow + m0n);
            rb0 = bs[0]; rb1 = bs[1];
        }

        // ---- QK^T swapped: s[ms][r] = S[key = ms*16+lg*4+r][q = lr]
        f32x4 s[4];
        __builtin_amdgcn_s_setprio(1);
        #pragma unroll
        for (int ms = 0; ms < 4; ++ms) {
            half8_t k0 = *(const half8_t*)&Kl[ms * 16 + lr][lg * 8];
            half8_t k1 = *(const half8_t*)&Kl[ms * 16 + lr][32 + lg * 8];
            f32x4 acc = {0.f, 0.f, 0.f, 0.f};
            acc = __builtin_amdgcn_mfma_f32_16x16x32_f16(k0, qf0, acc, 0, 0, 0);
            acc = __builtin_amdgcn_mfma_f32_16x16x32_f16(k1, qf1, acc, 0, 0, 0);
            s[ms] = acc;
        }
        __builtin_amdgcn_s_setprio(0);

        // ---- bias add (vector b64 reads; row = q, cols = 4 consecutive keys)
        #pragma unroll
        for (int ms = 0; ms < 4; ++ms) {
            half4_t b4 = *(const half4_t*)&Bl[w * 16 + lr][ms * 16 + lg * 4];
            s[ms][0] += (float)b4[0];
            s[ms][1] += (float)b4[1];
            s[ms][2] += (float)b4[2];
            s[ms][3] += (float)b4[3];
        }
        // ---- key-validity mask (uniform branch, last chunk only)
        if (c == 12) {
            #pragma unroll
            for (int ms = 0; ms < 4; ++ms)
                #pragma unroll
                for (int r = 0; r < 4; ++r)
                    if (ms * 16 + lg * 4 + r >= 17) s[ms][r] = -1e30f;
        }

        // ---- online softmax (per-lane row; reduce across lg lanes)
        float smax = fmaxf(fmaxf(fmaxf(s[0][0], s[0][1]), fmaxf(s[0][2], s[0][3])),
                           fmaxf(fmaxf(s[1][0], s[1][1]), fmaxf(s[1][2], s[1][3])));
        smax = fmaxf(smax, fmaxf(fmaxf(fmaxf(s[2][0], s[2][1]), fmaxf(s[2][2], s[2][3])),
                                 fmaxf(fmaxf(s[3][0], s[3][1]), fmaxf(s[3][2], s[3][3]))));
        smax = fmaxf(smax, __shfl_xor(smax, 16));
        smax = fmaxf(smax, __shfl_xor(smax, 32));

        if (__any(smax > m_run + 8.f)) {       // defer-max: rescale rarely
            const float mn    = fmaxf(m_run, smax);
            const float alpha = exp2f(m_run - mn);
            m_run = mn;
            l_run *= alpha;
            const float a0 = __shfl(alpha, lg * 4 + 0);
            const float a1 = __shfl(alpha, lg * 4 + 1);
            const float a2 = __shfl(alpha, lg * 4 + 2);
            const float a3 = __shfl(alpha, lg * 4 + 3);
            O0[0]*=a0; O0[1]*=a1; O0[2]*=a2; O0[3]*=a3;
            O1[0]*=a0; O1[1]*=a1; O1[2]*=a2; O1[3]*=a3;
            O2[0]*=a0; O2[1]*=a1; O2[2]*=a2; O2[3]*=a3;
            O3[0]*=a0; O3[1]*=a1; O3[2]*=a2; O3[3]*=a3;
        }

        float p[4][4];
        float psum = 0.f;
        #pragma unroll
        for (int ms = 0; ms < 4; ++ms)
            #pragma unroll
            for (int r = 0; r < 4; ++r) {
                p[ms][r] = exp2f(s[ms][r] - m_run);
                psum += p[ms][r];
            }
        psum += __shfl_xor(psum, 16);
        psum += __shfl_xor(psum, 32);
        l_run += psum;

        // ---- pack P into lane-local A-frags (V k-axis permuted to match)
        half8_t pa0 = { (_Float16)p[0][0], (_Float16)p[0][1], (_Float16)p[0][2], (_Float16)p[0][3],
                        (_Float16)p[1][0], (_Float16)p[1][1], (_Float16)p[1][2], (_Float16)p[1][3] };
        half8_t pa1 = { (_Float16)p[2][0], (_Float16)p[2][1], (_Float16)p[2][2], (_Float16)p[2][3],
                        (_Float16)p[3][0], (_Float16)p[3][1], (_Float16)p[3][2], (_Float16)p[3][3] };

        // ---- PV: B-frag = V^T with permuted key columns (two b64 per frag)
        __builtin_amdgcn_s_setprio(1);
        #pragma unroll
        for (int ds = 0; ds < 4; ++ds) {
            const _Float16* vr = &Vl[ds * 16 + lr][0];
            half4_t v00 = *(const half4_t*)&vr[lg * 4];
            half4_t v01 = *(const half4_t*)&vr[16 + lg * 4];
            half4_t v10 = *(const half4_t*)&vr[32 + lg * 4];
            half4_t v11 = *(const half4_t*)&vr[48 + lg * 4];
            half8_t vf0 = __builtin_shufflevector(v00, v01, 0, 1, 2, 3, 4, 5, 6, 7);
            half8_t vf1 = __builtin_shufflevector(v10, v11, 0, 1, 2, 3, 4, 5, 6, 7);
            f32x4& Od = (ds == 0 ? O0 : ds == 1 ? O1 : ds == 2 ? O2 : O3);
            Od = __builtin_amdgcn_mfma_f32_16x16x32_f16(pa0, vf0, Od, 0, 0, 0);
            Od = __builtin_amdgcn_mfma_f32_16x16x32_f16(pa1, vf1, Od, 0, 0, 0);
        }
        __builtin_amdgcn_s_setprio(0);
        __syncthreads();
    }

    // ---- epilogue: O rows = q-rows w*16 + lg*4 + r, col d = ds*16 + lr
    const int bb = bh / H_;
    #pragma unroll
    for (int r = 0; r < 4; ++r) {
        const int n = n0 + w * 16 + lg * 4 + r;
        if (n >= N_) continue;
        const float lv  = __shfl(l_run, lg * 4 + r);
        const float inv = 1.f / lv;
        _Float16* dst = aoh + ((size_t)(bb * N_ + n)) * C_ + h * HD_;
        dst[0 * 16 + lr] = (_Float16)(O0[r] * inv);
        dst[1 * 16 + lr] = (_Float16)(O1[r] * inv);
        dst[2 * 16 + lr] = (_Float16)(O2[r] * inv);
        dst[3 * 16 + lr] = (_Float16)(O3[r] * inv);
    }
}

// ---------------------------------------------------------------------------
// K4: proj MFMA GEMM: out = AO @ Wp^T + bias (fp32 out)
// ---------------------------------------------------------------------------
__global__ __launch_bounds__(256) void proj_gemm_mfma(
    const _Float16* __restrict__ A, const _Float16* __restrict__ Bw,
    const float* __restrict__ bias, float* __restrict__ out)
{
    __shared__ _Float16 Asl[128 * 32];
    __shared__ _Float16 Bsl[128 * 32];

    const int t  = threadIdx.x;
    const int w  = t >> 6;
    const int l  = t & 63;
    const int lr = l & 15;
    const int lg = l >> 4;
    const int wm = (w >> 1) * 64;
    const int wn = (w & 1) * 64;
    const int n0 = blockIdx.x * 128;
    const int m0 = blockIdx.y * 128;

    const int f1 = t + 256;
    const int ar0 = t >> 2,  ac0 = (t & 3) * 8;
    const int ar1 = f1 >> 2, ac1 = (f1 & 3) * 8;
    const _Float16* Ag0 = A  + (size_t)(m0 + ar0) * 768 + ac0;
    const _Float16* Ag1 = A  + (size_t)(m0 + ar1) * 768 + ac1;
    const _Float16* Bg0 = Bw + (size_t)(n0 + ar0) * 768 + ac0;
    const _Float16* Bg1 = Bw + (size_t)(n0 + ar1) * 768 + ac1;
    _Float16* Al0 = &Asl[t * 8];
    _Float16* Al1 = &Asl[f1 * 8];
    _Float16* Bl0 = &Bsl[t * 8];
    _Float16* Bl1 = &Bsl[f1 * 8];

    f32x4 acc[4][4];
    #pragma unroll
    for (int i = 0; i < 4; ++i)
        #pragma unroll
        for (int j = 0; j < 4; ++j) acc[i][j] = (f32x4){0.f, 0.f, 0.f, 0.f};

    for (int k0 = 0; k0 < 768; k0 += 32) {
        gl16(Ag0 + k0, Al0); gl16(Ag1 + k0, Al1);
        gl16(Bg0 + k0, Bl0); gl16(Bg1 + k0, Bl1);
        __syncthreads();
        half8_t af[4], bf[4];
        #pragma unroll
        for (int i = 0; i < 4; ++i)
            af[i] = *(const half8_t*)&Asl[(wm + i * 16 + lr) * 32 + lg * 8];
        #pragma unroll
        for (int j = 0; j < 4; ++j)
            bf[j] = *(const half8_t*)&Bsl[(wn + j * 16 + lr) * 32 + lg * 8];
        __builtin_amdgcn_s_setprio(1);
        #pragma unroll
        for (int i = 0; i < 4; ++i)
            #pragma unroll
            for (int j = 0; j < 4; ++j)
                acc[i][j] = __builtin_amdgcn_mfma_f32_16x16x32_f16(af[i], bf[j], acc[i][j], 0, 0, 0);
        __builtin_amdgcn_s_setprio(0);
        __syncthreads();
    }

    float bj[4];
    #pragma unroll
    for (int j = 0; j < 4; ++j) bj[j] = bias[n0 + wn + j * 16 + lr];
    #pragma unroll
    for (int i = 0; i < 4; ++i) {
        #pragma unroll
        for (int r = 0; r < 4; ++r) {
            const int m = m0 + wm + i * 16 + lg * 4 + r;
            if (m >= M_) continue;
            #pragma unroll
            for (int j = 0; j < 4; ++j) {
                const int n = n0 + wn + j * 16 + lr;
                out[(size_t)m * 768 + n] = acc[i][j][r] + bj[j];
            }
        }
    }
}

// ---------------------------------------------------------------------------
extern "C" void kernel_launch(void* const* d_in, const int* in_sizes, int n_in,
                              void* d_out, int out_size, void* d_ws, size_t ws_size,
                              hipStream_t stream)
{
    const float* x     = (const float*)d_in[0];
    const float* qkv_w = (const float*)d_in[1];
    const float* pe    = (const float*)d_in[2];
    const float* pw    = (const float*)d_in[3];
    const float* pjw   = (const float*)d_in[4];
    const float* pjb   = (const float*)d_in[5];
    float* out = (float*)d_out;

    _Float16* wsh  = (_Float16*)d_ws;
    _Float16* qh   = wsh + OFF_Q;
    _Float16* kh   = wsh + OFF_K;
    _Float16* vth  = wsh + OFF_VT;
    _Float16* posh = wsh + OFF_POS;
    _Float16* xf   = wsh + OFF_XF;
    _Float16* aoh  = wsh + OFF_AO;       // aliases xf (x dead after qkv_gemm)
    _Float16* wqf  = wsh + OFF_WQ;
    _Float16* wpf  = wsh + OFF_WP;

    convert_f16<<<dim3(NTOT4 / 256), 256, 0, stream>>>(x, qkv_w, pjw, xf, wqf, wpf);
    qkv_gemm_mfma<<<dim3(18, 99), 256, 0, stream>>>(
        xf, wqf, (__half*)qh, (__half*)kh, (__half*)vth);
    pos_kernel<<<dim3((N_ * N_ + 255) / 256), 256, 0, stream>>>(pe, pw, (__half*)posh);
    attn_mfma<<<dim3(13 * 12 * 16), 256, 0, stream>>>(qh, kh, vth, posh, aoh);
    proj_gemm_mfma<<<dim3(6, 99), 256, 0, stream>>>(aoh, wpf, pjb, out);
}

// Round 6
// 270.064 us; speedup vs baseline: 5.9404x; 1.0762x over previous
//
#include <hip/hip_runtime.h>
#include <hip/hip_fp16.h>

#define B_ 16
#define N_ 785
#define C_ 768
#define H_ 12
#define HD_ 64
#define P_ 48
#define M_ (B_*N_)      // 12560
#define POSW 832        // padded row stride (halves) for pos bias (13*64)
#define VTW  832        // padded row stride (halves) for V^T
#define SLOG2E 0.1803368801111244f   // (hd^-0.5) * log2(e)

// ws layout (fp16 element offsets)
#define OFF_Q   0                    //  9,646,080
#define OFF_K   9646080              //  9,646,080
#define OFF_VT  19292160             // 10,223,616 (16*12*64*832)
#define OFF_POS 29515776             //  7,837,440 (12*785*832)
#define OFF_XF  37353216             //  9,732,096 (12672*768) — x-f16, later attn-out
#define OFF_AO  OFF_XF               //  alias: x dead after qkv_gemm
#define OFF_WQ  47085312             //  1,769,472 (2304*768)
#define OFF_WP  48854784             //    589,824 (768*768)  end: 49,444,608 halves

struct __align__(16) Half8 { __half h[8]; };
typedef _Float16 half8_t __attribute__((ext_vector_type(8)));
typedef _Float16 half4_t __attribute__((ext_vector_type(4)));
typedef float f32x4 __attribute__((ext_vector_type(4)));

__device__ __forceinline__ void gl16(const void* g, void* l) {
    __builtin_amdgcn_global_load_lds(
        (const __attribute__((address_space(1))) void*)g,
        (__attribute__((address_space(3))) void*)l, 16, 0, 0);
}

// bijective XCD-chunked swizzle (m204): dispatch id -> contiguous per-XCD id
__device__ __forceinline__ int xcd_swz(int o, int nwg) {
    const int q = nwg >> 3, r = nwg & 7;
    const int xcd = o & 7, idx = o >> 3;
    const int base = xcd < r ? xcd * (q + 1) : r * (q + 1) + (xcd - r) * q;
    return base + idx;
}

// ---------------------------------------------------------------------------
// K0: fp32 -> fp16 convert of x, qkv_w, proj_w
// ---------------------------------------------------------------------------
#define NX4 2411520
#define NQ4 442368
#define NP4 147456
#define NTOT4 (NX4+NQ4+NP4)   // 3,001,344 = 11724 * 256

__global__ __launch_bounds__(256) void convert_f16(
    const float* __restrict__ x, const float* __restrict__ wq,
    const float* __restrict__ wp, _Float16* __restrict__ xo,
    _Float16* __restrict__ wqo, _Float16* __restrict__ wpo)
{
    int i = blockIdx.x * 256 + threadIdx.x;
    const float4* s; _Float16* d; int o;
    if (i < NX4)            { s = (const float4*)x;  d = xo;  o = i; }
    else if (i < NX4 + NQ4) { s = (const float4*)wq; d = wqo; o = i - NX4; }
    else                    { s = (const float4*)wp; d = wpo; o = i - NX4 - NQ4; }
    float4 v = s[o];
    half4_t h = { (_Float16)v.x, (_Float16)v.y, (_Float16)v.z, (_Float16)v.w };
    *(half4_t*)&d[o * 4] = h;
}

// ---------------------------------------------------------------------------
// K1: qkv MFMA GEMM, double-buffered LDS (T3-min) + XCD swizzle (T1)
// ---------------------------------------------------------------------------
#define QKV_NWG (18 * 99)

__global__ __launch_bounds__(256) void qkv_gemm_mfma(
    const _Float16* __restrict__ A, const _Float16* __restrict__ Bw,
    __half* __restrict__ qh, __half* __restrict__ kh, __half* __restrict__ vth)
{
    __shared__ _Float16 Asl[2][128 * 32];
    __shared__ _Float16 Bsl[2][128 * 32];

    const int t  = threadIdx.x;
    const int w  = t >> 6;
    const int l  = t & 63;
    const int lr = l & 15;
    const int lg = l >> 4;
    const int wm = (w >> 1) * 64;
    const int wn = (w & 1) * 64;

    const int g  = xcd_swz(blockIdx.x, QKV_NWG);
    const int nt = g % 18;              // n fastest: same-A blocks adjacent per XCD
    const int n0 = nt * 128;
    const int m0 = (g / 18) * 128;

    const int f1 = t + 256;
    const int ar0 = t >> 2,  ac0 = (t & 3) * 8;
    const int ar1 = f1 >> 2, ac1 = (f1 & 3) * 8;
    const _Float16* Ag0 = A  + (size_t)(m0 + ar0) * 768 + ac0;
    const _Float16* Ag1 = A  + (size_t)(m0 + ar1) * 768 + ac1;
    const _Float16* Bg0 = Bw + (size_t)(n0 + ar0) * 768 + ac0;
    const _Float16* Bg1 = Bw + (size_t)(n0 + ar1) * 768 + ac1;

    f32x4 acc[4][4];
    #pragma unroll
    for (int i = 0; i < 4; ++i)
        #pragma unroll
        for (int j = 0; j < 4; ++j) acc[i][j] = (f32x4){0.f, 0.f, 0.f, 0.f};

    // prologue: stage K-tile 0 into buf 0
    gl16(Ag0, &Asl[0][t * 8]); gl16(Ag1, &Asl[0][f1 * 8]);
    gl16(Bg0, &Bsl[0][t * 8]); gl16(Bg1, &Bsl[0][f1 * 8]);
    __syncthreads();

    #pragma unroll 2
    for (int it = 0; it < 24; ++it) {
        const int cur = it & 1;
        if (it < 23) {                  // prefetch next tile; stays in flight
            const int kn = (it + 1) * 32;
            gl16(Ag0 + kn, &Asl[cur ^ 1][t * 8]); gl16(Ag1 + kn, &Asl[cur ^ 1][f1 * 8]);
            gl16(Bg0 + kn, &Bsl[cur ^ 1][t * 8]); gl16(Bg1 + kn, &Bsl[cur ^ 1][f1 * 8]);
        }
        half8_t af[4], bf[4];
        #pragma unroll
        for (int i = 0; i < 4; ++i)
            af[i] = *(const half8_t*)&Asl[cur][(wm + i * 16 + lr) * 32 + lg * 8];
        #pragma unroll
        for (int j = 0; j < 4; ++j)
            bf[j] = *(const half8_t*)&Bsl[cur][(wn + j * 16 + lr) * 32 + lg * 8];
        __builtin_amdgcn_s_setprio(1);
        #pragma unroll
        for (int i = 0; i < 4; ++i)
            #pragma unroll
            for (int j = 0; j < 4; ++j)
                acc[i][j] = __builtin_amdgcn_mfma_f32_16x16x32_f16(af[i], bf[j], acc[i][j], 0, 0, 0);
        __builtin_amdgcn_s_setprio(0);
        __syncthreads();                // drains vmcnt (prefetch) + lgkm, 1/iter
    }

    const int tsel  = nt / 6;          // 0=q 1=k 2=v
    const int nbase = n0 - tsel * 768;
    #pragma unroll
    for (int i = 0; i < 4; ++i) {
        #pragma unroll
        for (int r = 0; r < 4; ++r) {
            const int m = m0 + wm + i * 16 + lg * 4 + r;
            if (m >= M_) continue;
            const int bb = m / N_, nn = m - bb * N_;
            #pragma unroll
            for (int j = 0; j < 4; ++j) {
                const int nsec = nbase + wn + j * 16 + lr;
                const int hh = nsec >> 6, dd = nsec & 63;
                const float v = acc[i][j][r];
                if (tsel == 0)
                    qh[((size_t)(bb * H_ + hh) * N_ + nn) * HD_ + dd] = __float2half(v * SLOG2E);
                else if (tsel == 1)
                    kh[((size_t)(bb * H_ + hh) * N_ + nn) * HD_ + dd] = __float2half(v);
                else
                    vth[((size_t)(bb * H_ + hh) * HD_ + dd) * VTW + nn] = __float2half(v);
            }
        }
    }
}

// ---------------------------------------------------------------------------
// K2: pos bias (scaled by SCALE*log2e): posh[h][n][m]
// ---------------------------------------------------------------------------
__global__ __launch_bounds__(256) void pos_kernel(
    const float* __restrict__ pe, const float* __restrict__ pw,
    __half* __restrict__ posh)
{
    __shared__ float W[H_][P_];
    const int t = threadIdx.x;
    for (int i = t; i < H_ * P_; i += 256) W[i / P_][i % P_] = pw[i];
    __syncthreads();
    int nm = blockIdx.x * 256 + t;
    if (nm >= N_ * N_) return;
    float e[48];
    const float4* src = (const float4*)(pe + (size_t)nm * 48);
    #pragma unroll
    for (int i = 0; i < 12; ++i) {
        float4 v = src[i];
        e[4*i] = v.x; e[4*i+1] = v.y; e[4*i+2] = v.z; e[4*i+3] = v.w;
    }
    int n = nm / N_, m = nm - n * N_;
    #pragma unroll
    for (int hh = 0; hh < H_; ++hh) {
        float s = 0.f;
        #pragma unroll
        for (int p = 0; p < 48; ++p) s = fmaf(e[p], W[hh][p], s);
        posh[((size_t)hh * N_ + n) * POSW + m] = __float2half(s * SLOG2E);
    }
}

// ---------------------------------------------------------------------------
// K3: MFMA flash attention, swapped-QK^T (q-row lane-local softmax),
//     lane-local P via V column permutation, exp2 domain, defer-max,
//     register prefetch of next K/V/bias chunk.
// ---------------------------------------------------------------------------
__global__ __launch_bounds__(256) void attn_mfma(
    const _Float16* __restrict__ qh, const _Float16* __restrict__ kh,
    const _Float16* __restrict__ vt, const _Float16* __restrict__ posh,
    _Float16* __restrict__ aoh)
{
    __shared__ _Float16 Kl[64][72];          // keys  [m][d]
    __shared__ _Float16 Vl[64][72];          // V^T   [d][m]
    __shared__ _Float16 Bl[64][72];          // bias  [qrow][m]

    const int t  = threadIdx.x;
    const int w  = t >> 6;                   // wave 0..3
    const int l  = t & 63;
    const int lr = l & 15;
    const int lg = l >> 4;

    const int g   = blockIdx.x;
    const int b   = g & 15;
    const int grp = g >> 4;
    const int qt  = grp / 12;
    const int h   = grp - qt * 12;
    const int bh  = b * H_ + h;
    const int n0  = qt * 64;

    const int qrow = n0 + w * 16 + lr;
    const int qrc  = qrow < N_ ? qrow : N_ - 1;
    const _Float16* qbase = qh + ((size_t)bh * N_ + qrc) * HD_;
    const half8_t qf0 = *(const half8_t*)(qbase + lg * 8);
    const half8_t qf1 = *(const half8_t*)(qbase + 32 + lg * 8);

    f32x4 O0 = {0.f,0.f,0.f,0.f}, O1 = O0, O2 = O0, O3 = O0;
    float m_run = -1e30f;
    float l_run = 0.f;

    const int srow = t >> 2;
    const int scol = (t & 3) * 16;
    const _Float16* kRow = kh + ((size_t)bh * N_) * HD_ + scol;
    const _Float16* vRow = vt + ((size_t)bh * HD_ + srow) * VTW + scol;
    const _Float16* bRow = posh + ((size_t)h * N_ + (n0 + srow < N_ ? n0 + srow : N_ - 1)) * POSW + scol;

    half8_t rk0, rk1, rv0, rv1, rb0, rb1;
    {
        const int gm = srow < N_ ? srow : N_ - 1;
        const half8_t* ks = (const half8_t*)(kRow + (size_t)gm * HD_);
        rk0 = ks[0]; rk1 = ks[1];
        const half8_t* vs = (const half8_t*)vRow;
        rv0 = vs[0]; rv1 = vs[1];
        const half8_t* bs = (const half8_t*)bRow;
        rb0 = bs[0]; rb1 = bs[1];
    }

    for (int c = 0; c < 13; ++c) {
        *(half8_t*)&Kl[srow][scol]     = rk0;
        *(half8_t*)&Kl[srow][scol + 8] = rk1;
        *(half8_t*)&Vl[srow][scol]     = rv0;
        *(half8_t*)&Vl[srow][scol + 8] = rv1;
        *(half8_t*)&Bl[srow][scol]     = rb0;
        *(half8_t*)&Bl[srow][scol + 8] = rb1;
        __syncthreads();

        if (c < 12) {
            const int m0n = (c + 1) * 64;
            const int gm  = (m0n + srow) < N_ ? (m0n + srow) : N_ - 1;
            const half8_t* ks = (const half8_t*)(kRow + (size_t)gm * HD_);
            rk0 = ks[0]; rk1 = ks[1];
            const half8_t* vs = (const half8_t*)(vRow + m0n);
            rv0 = vs[0]; rv1 = vs[1];
            const half8_t* bs = (const half8_t*)(bRow + m0n);
            rb0 = bs[0]; rb1 = bs[1];
        }

        f32x4 s[4];
        __builtin_amdgcn_s_setprio(1);
        #pragma unroll
        for (int ms = 0; ms < 4; ++ms) {
            half8_t k0 = *(const half8_t*)&Kl[ms * 16 + lr][lg * 8];
            half8_t k1 = *(const half8_t*)&Kl[ms * 16 + lr][32 + lg * 8];
            f32x4 acc = {0.f, 0.f, 0.f, 0.f};
            acc = __builtin_amdgcn_mfma_f32_16x16x32_f16(k0, qf0, acc, 0, 0, 0);
            acc = __builtin_amdgcn_mfma_f32_16x16x32_f16(k1, qf1, acc, 0, 0, 0);
            s[ms] = acc;
        }
        __builtin_amdgcn_s_setprio(0);

        #pragma unroll
        for (int ms = 0; ms < 4; ++ms) {
            half4_t b4 = *(const half4_t*)&Bl[w * 16 + lr][ms * 16 + lg * 4];
            s[ms][0] += (float)b4[0];
            s[ms][1] += (float)b4[1];
            s[ms][2] += (float)b4[2];
            s[ms][3] += (float)b4[3];
        }
        if (c == 12) {
            #pragma unroll
            for (int ms = 0; ms < 4; ++ms)
                #pragma unroll
                for (int r = 0; r < 4; ++r)
                    if (ms * 16 + lg * 4 + r >= 17) s[ms][r] = -1e30f;
        }

        float smax = fmaxf(fmaxf(fmaxf(s[0][0], s[0][1]), fmaxf(s[0][2], s[0][3])),
                           fmaxf(fmaxf(s[1][0], s[1][1]), fmaxf(s[1][2], s[1][3])));
        smax = fmaxf(smax, fmaxf(fmaxf(fmaxf(s[2][0], s[2][1]), fmaxf(s[2][2], s[2][3])),
                                 fmaxf(fmaxf(s[3][0], s[3][1]), fmaxf(s[3][2], s[3][3]))));
        smax = fmaxf(smax, __shfl_xor(smax, 16));
        smax = fmaxf(smax, __shfl_xor(smax, 32));

        if (__any(smax > m_run + 8.f)) {
            const float mn    = fmaxf(m_run, smax);
            const float alpha = exp2f(m_run - mn);
            m_run = mn;
            l_run *= alpha;
            const float a0 = __shfl(alpha, lg * 4 + 0);
            const float a1 = __shfl(alpha, lg * 4 + 1);
            const float a2 = __shfl(alpha, lg * 4 + 2);
            const float a3 = __shfl(alpha, lg * 4 + 3);
            O0[0]*=a0; O0[1]*=a1; O0[2]*=a2; O0[3]*=a3;
            O1[0]*=a0; O1[1]*=a1; O1[2]*=a2; O1[3]*=a3;
            O2[0]*=a0; O2[1]*=a1; O2[2]*=a2; O2[3]*=a3;
            O3[0]*=a0; O3[1]*=a1; O3[2]*=a2; O3[3]*=a3;
        }

        float p[4][4];
        float psum = 0.f;
        #pragma unroll
        for (int ms = 0; ms < 4; ++ms)
            #pragma unroll
            for (int r = 0; r < 4; ++r) {
                p[ms][r] = exp2f(s[ms][r] - m_run);
                psum += p[ms][r];
            }
        psum += __shfl_xor(psum, 16);
        psum += __shfl_xor(psum, 32);
        l_run += psum;

        half8_t pa0 = { (_Float16)p[0][0], (_Float16)p[0][1], (_Float16)p[0][2], (_Float16)p[0][3],
                        (_Float16)p[1][0], (_Float16)p[1][1], (_Float16)p[1][2], (_Float16)p[1][3] };
        half8_t pa1 = { (_Float16)p[2][0], (_Float16)p[2][1], (_Float16)p[2][2], (_Float16)p[2][3],
                        (_Float16)p[3][0], (_Float16)p[3][1], (_Float16)p[3][2], (_Float16)p[3][3] };

        __builtin_amdgcn_s_setprio(1);
        #pragma unroll
        for (int ds = 0; ds < 4; ++ds) {
            const _Float16* vr = &Vl[ds * 16 + lr][0];
            half4_t v00 = *(const half4_t*)&vr[lg * 4];
            half4_t v01 = *(const half4_t*)&vr[16 + lg * 4];
            half4_t v10 = *(const half4_t*)&vr[32 + lg * 4];
            half4_t v11 = *(const half4_t*)&vr[48 + lg * 4];
            half8_t vf0 = __builtin_shufflevector(v00, v01, 0, 1, 2, 3, 4, 5, 6, 7);
            half8_t vf1 = __builtin_shufflevector(v10, v11, 0, 1, 2, 3, 4, 5, 6, 7);
            f32x4& Od = (ds == 0 ? O0 : ds == 1 ? O1 : ds == 2 ? O2 : O3);
            Od = __builtin_amdgcn_mfma_f32_16x16x32_f16(pa0, vf0, Od, 0, 0, 0);
            Od = __builtin_amdgcn_mfma_f32_16x16x32_f16(pa1, vf1, Od, 0, 0, 0);
        }
        __builtin_amdgcn_s_setprio(0);
        __syncthreads();
    }

    const int bb = bh / H_;
    #pragma unroll
    for (int r = 0; r < 4; ++r) {
        const int n = n0 + w * 16 + lg * 4 + r;
        if (n >= N_) continue;
        const float lv  = __shfl(l_run, lg * 4 + r);
        const float inv = 1.f / lv;
        _Float16* dst = aoh + ((size_t)(bb * N_ + n)) * C_ + h * HD_;
        dst[0 * 16 + lr] = (_Float16)(O0[r] * inv);
        dst[1 * 16 + lr] = (_Float16)(O1[r] * inv);
        dst[2 * 16 + lr] = (_Float16)(O2[r] * inv);
        dst[3 * 16 + lr] = (_Float16)(O3[r] * inv);
    }
}

// ---------------------------------------------------------------------------
// K4: proj MFMA GEMM, double-buffered + XCD swizzle: out = AO @ Wp^T + bias
// ---------------------------------------------------------------------------
#define PROJ_NWG (6 * 99)

__global__ __launch_bounds__(256) void proj_gemm_mfma(
    const _Float16* __restrict__ A, const _Float16* __restrict__ Bw,
    const float* __restrict__ bias, float* __restrict__ out)
{
    __shared__ _Float16 Asl[2][128 * 32];
    __shared__ _Float16 Bsl[2][128 * 32];

    const int t  = threadIdx.x;
    const int w  = t >> 6;
    const int l  = t & 63;
    const int lr = l & 15;
    const int lg = l >> 4;
    const int wm = (w >> 1) * 64;
    const int wn = (w & 1) * 64;

    const int g  = xcd_swz(blockIdx.x, PROJ_NWG);
    const int n0 = (g % 6) * 128;
    const int m0 = (g / 6) * 128;

    const int f1 = t + 256;
    const int ar0 = t >> 2,  ac0 = (t & 3) * 8;
    const int ar1 = f1 >> 2, ac1 = (f1 & 3) * 8;
    const _Float16* Ag0 = A  + (size_t)(m0 + ar0) * 768 + ac0;
    const _Float16* Ag1 = A  + (size_t)(m0 + ar1) * 768 + ac1;
    const _Float16* Bg0 = Bw + (size_t)(n0 + ar0) * 768 + ac0;
    const _Float16* Bg1 = Bw + (size_t)(n0 + ar1) * 768 + ac1;

    f32x4 acc[4][4];
    #pragma unroll
    for (int i = 0; i < 4; ++i)
        #pragma unroll
        for (int j = 0; j < 4; ++j) acc[i][j] = (f32x4){0.f, 0.f, 0.f, 0.f};

    gl16(Ag0, &Asl[0][t * 8]); gl16(Ag1, &Asl[0][f1 * 8]);
    gl16(Bg0, &Bsl[0][t * 8]); gl16(Bg1, &Bsl[0][f1 * 8]);
    __syncthreads();

    #pragma unroll 2
    for (int it = 0; it < 24; ++it) {
        const int cur = it & 1;
        if (it < 23) {
            const int kn = (it + 1) * 32;
            gl16(Ag0 + kn, &Asl[cur ^ 1][t * 8]); gl16(Ag1 + kn, &Asl[cur ^ 1][f1 * 8]);
            gl16(Bg0 + kn, &Bsl[cur ^ 1][t * 8]); gl16(Bg1 + kn, &Bsl[cur ^ 1][f1 * 8]);
        }
        half8_t af[4], bf[4];
        #pragma unroll
        for (int i = 0; i < 4; ++i)
            af[i] = *(const half8_t*)&Asl[cur][(wm + i * 16 + lr) * 32 + lg * 8];
        #pragma unroll
        for (int j = 0; j < 4; ++j)
            bf[j] = *(const half8_t*)&Bsl[cur][(wn + j * 16 + lr) * 32 + lg * 8];
        __builtin_amdgcn_s_setprio(1);
        #pragma unroll
        for (int i = 0; i < 4; ++i)
            #pragma unroll
            for (int j = 0; j < 4; ++j)
                acc[i][j] = __builtin_amdgcn_mfma_f32_16x16x32_f16(af[i], bf[j], acc[i][j], 0, 0, 0);
        __builtin_amdgcn_s_setprio(0);
        __syncthreads();
    }

    float bj[4];
    #pragma unroll
    for (int j = 0; j < 4; ++j) bj[j] = bias[n0 + wn + j * 16 + lr];
    #pragma unroll
    for (int i = 0; i < 4; ++i) {
        #pragma unroll
        for (int r = 0; r < 4; ++r) {
            const int m = m0 + wm + i * 16 + lg * 4 + r;
            if (m >= M_) continue;
            #pragma unroll
            for (int j = 0; j < 4; ++j) {
                const int n = n0 + wn + j * 16 + lr;
                out[(size_t)m * 768 + n] = acc[i][j][r] + bj[j];
            }
        }
    }
}

// ---------------------------------------------------------------------------
extern "C" void kernel_launch(void* const* d_in, const int* in_sizes, int n_in,
                              void* d_out, int out_size, void* d_ws, size_t ws_size,
                              hipStream_t stream)
{
    const float* x     = (const float*)d_in[0];
    const float* qkv_w = (const float*)d_in[1];
    const float* pe    = (const float*)d_in[2];
    const float* pw    = (const float*)d_in[3];
    const float* pjw   = (const float*)d_in[4];
    const float* pjb   = (const float*)d_in[5];
    float* out = (float*)d_out;

    _Float16* wsh  = (_Float16*)d_ws;
    _Float16* qh   = wsh + OFF_Q;
    _Float16* kh   = wsh + OFF_K;
    _Float16* vth  = wsh + OFF_VT;
    _Float16* posh = wsh + OFF_POS;
    _Float16* xf   = wsh + OFF_XF;
    _Float16* aoh  = wsh + OFF_AO;       // aliases xf (x dead after qkv_gemm)
    _Float16* wqf  = wsh + OFF_WQ;
    _Float16* wpf  = wsh + OFF_WP;

    convert_f16<<<dim3(NTOT4 / 256), 256, 0, stream>>>(x, qkv_w, pjw, xf, wqf, wpf);
    qkv_gemm_mfma<<<dim3(QKV_NWG), 256, 0, stream>>>(
        xf, wqf, (__half*)qh, (__half*)kh, (__half*)vth);
    pos_kernel<<<dim3((N_ * N_ + 255) / 256), 256, 0, stream>>>(pe, pw, (__half*)posh);
    attn_mfma<<<dim3(13 * 12 * 16), 256, 0, stream>>>(qh, kh, vth, posh, aoh);
    proj_gemm_mfma<<<dim3(PROJ_NWG), 256, 0, stream>>>(aoh, wpf, pjb, out);
}